// Round 3
// baseline (1586.268 us; speedup 1.0000x reference)
//
#include <hip/hip_runtime.h>
#include <hip/hip_bf16.h>
#include <math.h>

// Shapes
#define N_TRAIN 4096
#define N_FEAT  64
#define N_HID   256
#define ENC     256
#define N_ANTES 2048
#define ATT_H   256
#define MAX_LEN 16
#define NB      256      // persistent grid = #CUs; 93KB LDS forces 1 block/CU

typedef unsigned int u32;

__device__ __forceinline__ float fsig(float x)  { return 1.f / (1.f + __expf(-x)); }
__device__ __forceinline__ float ftanh(float x) { return 2.f / (1.f + __expf(-2.f * x)) - 1.f; }

// ---------------------------------------------------------------------------
// Tiled GEMM: C[m,n] = act(bias[n] + sum_k A[m,k] * B[n,k]); 64x64x16 tiles.
// ---------------------------------------------------------------------------
template <bool RELU>
__global__ __launch_bounds__(256) void gemm_abT(
    const float* __restrict__ A, const float* __restrict__ B,
    const float* __restrict__ bias, float* __restrict__ C,
    int M, int N, int K, int lda, int ldb, int ldc)
{
    __shared__ __align__(16) float As[16][68];
    __shared__ __align__(16) float Bs[16][68];
    const int tid = threadIdx.x;
    const int m0 = blockIdx.x * 64, n0 = blockIdx.y * 64;
    const int tx = tid & 15, ty = tid >> 4;
    const int kl = tid & 15, rl = tid >> 4;
    float acc[4][4] = {};

    for (int k0 = 0; k0 < K; k0 += 16) {
        #pragma unroll
        for (int pp = 0; pp < 4; ++pp) {
            int r = rl + pp * 16;
            As[kl][r] = A[(size_t)(m0 + r) * lda + k0 + kl];
            Bs[kl][r] = B[(size_t)(n0 + r) * ldb + k0 + kl];
        }
        __syncthreads();
        #pragma unroll
        for (int k = 0; k < 16; ++k) {
            float4 av = *(const float4*)&As[k][ty * 4];
            float4 bv = *(const float4*)&Bs[k][tx * 4];
            float a4[4] = {av.x, av.y, av.z, av.w};
            float b4[4] = {bv.x, bv.y, bv.z, bv.w};
            #pragma unroll
            for (int i = 0; i < 4; ++i)
                #pragma unroll
                for (int j = 0; j < 4; ++j)
                    acc[i][j] = fmaf(a4[i], b4[j], acc[i][j]);
        }
        __syncthreads();
    }
    #pragma unroll
    for (int i = 0; i < 4; ++i) {
        int m = m0 + ty * 4 + i;
        #pragma unroll
        for (int j = 0; j < 4; ++j) {
            int n = n0 + tx * 4 + j;
            float v = acc[i][j] + bias[n];
            if (RELU) v = fmaxf(v, 0.f);
            C[(size_t)m * ldc + n] = v;
        }
    }
}

// ---------------------------------------------------------------------------
// Split-K GEMM, KSPLIT=8 partials into P0(4)/P1(2)/P2(2). Grid (M/64,N/64,8).
// ---------------------------------------------------------------------------
#define KSPLIT 8
__global__ __launch_bounds__(256) void gemm_ab_splitk(
    const float* __restrict__ A, const float* __restrict__ B,
    float* __restrict__ P0, float* __restrict__ P1, float* __restrict__ P2,
    int M, int N, int K, int lda, int ldb, int ldc)
{
    __shared__ __align__(16) float As[16][68];
    __shared__ __align__(16) float Bs[16][64];
    const int tid = threadIdx.x;
    const int m0 = blockIdx.x * 64, n0 = blockIdx.y * 64;
    const int kchunk = K / KSPLIT;
    const int kbeg = blockIdx.z * kchunk, kend = kbeg + kchunk;
    const int tx = tid & 15, ty = tid >> 4;
    const int kl = tid & 15, rl = tid >> 4;
    const int kb = tid >> 6, nb = tid & 63;
    float acc[4][4] = {};

    for (int k0 = kbeg; k0 < kend; k0 += 16) {
        #pragma unroll
        for (int pp = 0; pp < 4; ++pp) {
            As[kl][rl + pp * 16] = A[(size_t)(m0 + rl + pp * 16) * lda + k0 + kl];
            Bs[kb + pp * 4][nb]  = B[(size_t)(k0 + kb + pp * 4) * ldb + n0 + nb];
        }
        __syncthreads();
        #pragma unroll
        for (int k = 0; k < 16; ++k) {
            float4 av = *(const float4*)&As[k][ty * 4];
            float4 bv = *(const float4*)&Bs[k][tx * 4];
            float a4[4] = {av.x, av.y, av.z, av.w};
            float b4[4] = {bv.x, bv.y, bv.z, bv.w};
            #pragma unroll
            for (int i = 0; i < 4; ++i)
                #pragma unroll
                for (int j = 0; j < 4; ++j)
                    acc[i][j] = fmaf(a4[i], b4[j], acc[i][j]);
        }
        __syncthreads();
    }
    const int SZ = ATT_H * N_ANTES;
    const int bz = blockIdx.z;
    float* Cp = (bz < 4) ? P0 + (size_t)bz * SZ
              : (bz < 6) ? P1 + (size_t)(bz - 4) * SZ
                         : P2 + (size_t)(bz - 6) * SZ;
    #pragma unroll
    for (int i = 0; i < 4; ++i)
        #pragma unroll
        for (int j = 0; j < 4; ++j)
            Cp[(size_t)(m0 + ty * 4 + i) * ldc + n0 + tx * 4 + j] = acc[i][j];
}

__global__ __launch_bounds__(256) void k_reduce(
    const float* __restrict__ P0, const float* __restrict__ P1,
    const float* __restrict__ P2, float* __restrict__ preT)
{
    int gid = blockIdx.x * 256 + threadIdx.x;
    const int SZ = ATT_H * N_ANTES;
    float s = ((P0[gid] + P0[gid + SZ]) + (P0[gid + 2 * SZ] + P0[gid + 3 * SZ]))
            + ((P1[gid] + P1[gid + SZ]) + (P2[gid] + P2[gid + SZ]));
    preT[gid] = s;
}

// ---------------------------------------------------------------------------
// rowsum[j] = sum_k w_ih[j, k]
// ---------------------------------------------------------------------------
__global__ __launch_bounds__(256) void k_rowsum(const float* __restrict__ w_ih,
                                                float* __restrict__ rowsum)
{
    __shared__ float red[256];
    const int j = blockIdx.x, tid = threadIdx.x;
    float s = 0.f;
    for (int i = tid; i < N_ANTES; i += 256) s += w_ih[(size_t)j * N_ANTES + i];
    red[tid] = s; __syncthreads();
    for (int off = 128; off > 0; off >>= 1) {
        if (tid < off) red[tid] += red[tid + off];
        __syncthreads();
    }
    if (tid == 0) rowsum[j] = red[0];
}

// ---------------------------------------------------------------------------
// wpkT[k*1024 + j] = w_hh[j*256 + k]   (k-major: coalesced per-k loads)
// ---------------------------------------------------------------------------
__global__ __launch_bounds__(256) void k_packT(const float* __restrict__ w_hh,
                                               float* __restrict__ wpkT)
{
    int gid = blockIdx.x * 256 + threadIdx.x;  // 0..262143
    int j = gid >> 8;
    int k = gid & 255;
    wpkT[(size_t)k * 1024 + j] = w_hh[gid];
}

// ---------------------------------------------------------------------------
// WbT[k*256 + j] = att_w1[j*(N_TRAIN+ENC) + N_TRAIN + k]
// ---------------------------------------------------------------------------
__global__ __launch_bounds__(256) void k_wbT(const float* __restrict__ att_w1,
                                             float* __restrict__ WbT)
{
    int gid = blockIdx.x * 256 + threadIdx.x;  // 0..65535
    int j = gid >> 8, k = gid & 255;
    WbT[(size_t)k * 256 + j] = att_w1[(size_t)j * (N_TRAIN + ENC) + N_TRAIN + k];
}

// ---------------------------------------------------------------------------
// preP[p*256 + j] = preT[j*2048 + p]; 64x64 LDS tiles. Grid (32, 4).
// ---------------------------------------------------------------------------
__global__ __launch_bounds__(256) void k_packPT(const float* __restrict__ preT,
                                                float* __restrict__ preP)
{
    __shared__ float tile[64][65];
    const int tid = threadIdx.x;
    const int p0 = blockIdx.x * 64;
    const int j0 = blockIdx.y * 64;
    const int tc = tid & 63, tr = tid >> 6;
    #pragma unroll
    for (int q = 0; q < 16; ++q)
        tile[tr + q * 4][tc] = preT[(size_t)(j0 + tr + q * 4) * N_ANTES + p0 + tc];
    __syncthreads();
    #pragma unroll
    for (int q = 0; q < 16; ++q)
        preP[(size_t)(p0 + tr + q * 4) * 256 + j0 + tc] = tile[tc][tr + q * 4];
}

// ---------------------------------------------------------------------------
// Grid barrier: generation-based, agent-scope atomics (release/acquire via
// gen; same coherence pattern as the proven last-block k_att handshake).
// ---------------------------------------------------------------------------
__device__ __forceinline__ void gsync(int* bar, int* gen, int target)
{
    __syncthreads();
    if (threadIdx.x == 0) {
        int prev = __hip_atomic_fetch_add(bar, 1, __ATOMIC_ACQ_REL,
                                          __HIP_MEMORY_SCOPE_AGENT);
        if (prev == NB - 1) {
            __hip_atomic_store(bar, 0, __ATOMIC_RELAXED, __HIP_MEMORY_SCOPE_AGENT);
            __hip_atomic_store(gen, target, __ATOMIC_RELEASE, __HIP_MEMORY_SCOPE_AGENT);
        } else {
            while (__hip_atomic_load(gen, __ATOMIC_ACQUIRE,
                                     __HIP_MEMORY_SCOPE_AGENT) < target)
                __builtin_amdgcn_s_sleep(1);
        }
    }
    __syncthreads();
}

// ---------------------------------------------------------------------------
// Persistent fused loop: all 16 LSTM+attention steps in one kernel.
// 256 blocks x 1024 threads, block b owns rows [16b,16b+16).
// h lives in LDS (h_lds[k][r], stride 20) across all steps; c in registers.
// Per step: z GEMM (thread=gate col j, 16 rows) -> z_lds exchange -> gates
// -> e atomic -> GRID SYNC -> u matvec -> 8 scores/block -> GRID SYNC ->
// redundant per-block softmax/argmax (bit-identical order to old k_att).
// ---------------------------------------------------------------------------
#define HSTR 20
__global__ __launch_bounds__(1024, 4) void k_loop(
    const float* __restrict__ h0,
    const float* __restrict__ wpkT, const float* __restrict__ rowsum,
    const float* __restrict__ b_ih, const float* __restrict__ b_hh,
    const float* __restrict__ S, const float* __restrict__ preP,
    const float* __restrict__ WbT, const float* __restrict__ att_b1,
    const float* __restrict__ att_w2, const float* __restrict__ att_b2,
    float* __restrict__ e_acc, float* __restrict__ scores,
    float* __restrict__ out, int* __restrict__ bar)
{
    __shared__ __align__(16) float h_lds[256 * HSTR];   // 20 KB
    __shared__ float z_lds[16 * 1024];                  // 64 KB
    __shared__ float red[1024];                         // 4 KB
    __shared__ float u_s[256];
    __shared__ float e_s[256];
    __shared__ int   sidx_s[256];

    const int tid = threadIdx.x;
    const int n0 = blockIdx.x * 16;
    const int p0 = blockIdx.x * 8;
    int* gen = bar + 1;
    int bar_target = 0;

    const float rs = rowsum[tid];
    const float bs = b_ih[tid] + b_hh[tid];
    const int jj = tid & 255, rbase = tid >> 8;

    // stage h0 -> h_lds[k][r]
    {
        const int k = tid & 255;
        #pragma unroll
        for (int q = 0; q < 4; ++q) {
            int r = rbase * 4 + q;
            h_lds[k * HSTR + r] = h0[(size_t)(n0 + r) * 256 + k];
        }
    }
    float c_reg[4] = {0.f, 0.f, 0.f, 0.f};
    int idx_prev = 0;
    __syncthreads();

    for (int t = 0; t < MAX_LEN; ++t) {
        // ---- x gather (uniform) ----
        float a[16];
        if (t > 0) {
            const float* Sc = S + idx_prev;
            #pragma unroll
            for (int r = 0; r < 16; ++r)
                a[r] = Sc[(size_t)(n0 + r) * N_ANTES];
        } else {
            #pragma unroll
            for (int r = 0; r < 16; ++r) a[r] = 1.f;
        }

        // ---- z GEMM: thread owns gate col j=tid over 16 rows ----
        float wbuf[4];
        #pragma unroll
        for (int i = 0; i < 4; ++i) wbuf[i] = wpkT[(size_t)i * 1024 + tid];
        float acc[16];
        #pragma unroll
        for (int r = 0; r < 16; ++r) acc[r] = fmaf(a[r], rs, bs);

        for (int k4 = 0; k4 < 256; k4 += 4) {
            #pragma unroll
            for (int u = 0; u < 4; ++u) {
                float w = wbuf[u];
                wbuf[u] = wpkT[(size_t)(k4 + u + 4) * 1024 + tid];  // pad rows ok
                const float4* hr = (const float4*)&h_lds[(k4 + u) * HSTR];
                float4 h0v = hr[0], h1v = hr[1], h2v = hr[2], h3v = hr[3];
                float hk[16] = {h0v.x, h0v.y, h0v.z, h0v.w,
                                h1v.x, h1v.y, h1v.z, h1v.w,
                                h2v.x, h2v.y, h2v.z, h2v.w,
                                h3v.x, h3v.y, h3v.z, h3v.w};
                #pragma unroll
                for (int r = 0; r < 16; ++r)
                    acc[r] = fmaf(w, hk[r], acc[r]);
            }
        }

        #pragma unroll
        for (int r = 0; r < 16; ++r) z_lds[r * 1024 + tid] = acc[r];
        __syncthreads();

        // ---- gates: thread (jj, rbase) does rows rbase*4..+3, col jj ----
        float esum = 0.f;
        float hn4[4];
        #pragma unroll
        for (int i = 0; i < 4; ++i) {
            int r = rbase * 4 + i;
            float zi = z_lds[r * 1024 + jj];
            float zf = z_lds[r * 1024 + 256 + jj];
            float zg = z_lds[r * 1024 + 512 + jj];
            float zo = z_lds[r * 1024 + 768 + jj];
            float cn = fsig(zf) * c_reg[i] + fsig(zi) * ftanh(zg);
            float hn = fsig(zo) * ftanh(cn);
            c_reg[i] = cn;
            hn4[i] = hn;
            esum += hn;
        }
        // update h in LDS (aligned: 80*jj + 16*rbase bytes)
        *(float4*)&h_lds[jj * HSTR + rbase * 4] =
            make_float4(hn4[0], hn4[1], hn4[2], hn4[3]);
        red[tid] = esum;
        __syncthreads();
        if (tid < 256) {
            float e = (red[tid] + red[tid + 256]) + (red[tid + 512] + red[tid + 768]);
            atomicAdd(&e_acc[t * 256 + tid], e);
        }

        gsync(bar, gen, ++bar_target);          // e_acc complete

        // ---- u matvec (threads 0..255; exact old k_att order) ----
        if (tid < 256)
            e_s[tid] = e_acc[t * 256 + tid] * (1.f / (float)N_TRAIN);
        __syncthreads();
        if (tid < 256) {
            float uacc = att_b1[tid];
            for (int k = 0; k < 256; ++k)
                uacc = fmaf(e_s[k], WbT[(size_t)k * 256 + tid], uacc);
            u_s[tid] = uacc;
        }
        __syncthreads();

        // ---- scores for p0..p0+7 (64 threads; j-split 8, old order) ----
        if (tid < 64) {
            int pl = tid & 7, jq = tid >> 3;
            int p = p0 + pl;
            float sc = 0.f;
            #pragma unroll 4
            for (int j = jq; j < 256; j += 8) {
                float v = preP[(size_t)p * 256 + j] + u_s[j];
                sc = fmaf(fmaxf(v, 0.f), att_w2[j], sc);
            }
            red[jq * 8 + pl] = sc;
        }
        __syncthreads();
        if (tid < 8) {
            float s = att_b2[0];
            #pragma unroll
            for (int q = 0; q < 8; ++q) s += red[q * 8 + tid];
            scores[p0 + tid] = s;
        }

        gsync(bar, gen, ++bar_target);          // all scores complete

        // ---- redundant per-block softmax+argmax (old k_att2 order) ----
        float sv[8];
        if (tid < 256) {
            #pragma unroll
            for (int i = 0; i < 8; ++i) sv[i] = scores[tid * 8 + i];
            float lmax = -INFINITY; int lidx = 0;
            #pragma unroll
            for (int i = 0; i < 8; ++i)
                if (sv[i] > lmax) { lmax = sv[i]; lidx = tid * 8 + i; }
            red[tid] = lmax; sidx_s[tid] = lidx;
        }
        __syncthreads();
        for (int off = 128; off > 0; off >>= 1) {
            if (tid < off) {
                float ov = red[tid + off]; int oi = sidx_s[tid + off];
                if (ov > red[tid] || (ov == red[tid] && oi < sidx_s[tid])) {
                    red[tid] = ov; sidx_s[tid] = oi;
                }
            }
            __syncthreads();
        }
        const float gmax = red[0];
        idx_prev = sidx_s[0];
        __syncthreads();

        if (tid < 256) {
            float lsum = 0.f;
            #pragma unroll
            for (int i = 0; i < 8; ++i) lsum += __expf(sv[i] - gmax);
            red[512 + tid] = lsum;
        }
        __syncthreads();
        for (int off = 128; off > 0; off >>= 1) {
            if (tid < off) red[512 + tid] += red[512 + tid + off];
            __syncthreads();
        }
        const float lse = gmax + logf(red[512]);

        if (blockIdx.x == 0 && tid < 256) {
            #pragma unroll
            for (int i = 0; i < 8; ++i)
                out[(size_t)t * N_ANTES + tid * 8 + i] = sv[i] - lse;
        }
        __syncthreads();
    }
}

// ---------------------------------------------------------------------------
extern "C" void kernel_launch(void* const* d_in, const int* in_sizes, int n_in,
                              void* d_out, int out_size, void* d_ws, size_t ws_size,
                              hipStream_t stream)
{
    (void)in_sizes; (void)n_in; (void)out_size; (void)ws_size;
    const float* context = (const float*)d_in[0];
    const float* S       = (const float*)d_in[1];
    const float* enc_w1  = (const float*)d_in[2];
    const float* enc_b1  = (const float*)d_in[3];
    const float* enc_w2  = (const float*)d_in[4];
    const float* enc_b2  = (const float*)d_in[5];
    const float* w_ih    = (const float*)d_in[6];
    const float* w_hh    = (const float*)d_in[7];
    const float* b_ih    = (const float*)d_in[8];
    const float* b_hh    = (const float*)d_in[9];
    const float* att_w1  = (const float*)d_in[10];
    const float* att_b1  = (const float*)d_in[11];
    const float* att_w2  = (const float*)d_in[12];
    const float* att_b2  = (const float*)d_in[13];
    float* out = (float*)d_out;
    float* ws  = (float*)d_ws;

    // ws layout (float offsets)
    float* h      = ws;                        // encoder out (P0 partials first)
    float* buf4M  = ws + 2097152;              // splitk P1, then hid1
    float* preT   = ws + 3145728;              // 524,288
    float* preP   = ws + 3670016;              // splitk P2, then preP [2048][256]
    float* wpkT   = ws + 4718592;              // 262,144 + 4,096 pad
    float* rowsum = ws + 4984832;              // 1,024
    float* e_acc  = ws + 4985856;              // 4,096
    float* scores = ws + 4989952;              // 2,048
    float* WbT    = ws + 4992000;              // 65,536
    int*   bar    = (int*)(ws + 4980736);      // {cnt, gen} in wpkT pad

    k_rowsum<<<1024, 256, 0, stream>>>(w_ih, rowsum);
    k_packT<<<1024, 256, 0, stream>>>(w_hh, wpkT);
    k_wbT<<<256, 256, 0, stream>>>(att_w1, WbT);

    // preT = Wa @ S (8 partials borrow h[2M], buf4M[1M], preP-slot[1M])
    dim3 g3(ATT_H / 64, N_ANTES / 64, KSPLIT);
    gemm_ab_splitk<<<g3, 256, 0, stream>>>(att_w1, S, ws /*P0 x4*/,
                                           buf4M /*P1 x2*/, preP /*P2 x2*/,
                                           ATT_H, N_ANTES, N_TRAIN,
                                           N_TRAIN + ENC, N_ANTES, N_ANTES);
    k_reduce<<<(ATT_H * N_ANTES) / 256, 256, 0, stream>>>(ws, buf4M, preP, preT);
    dim3 gP(N_ANTES / 64, ATT_H / 64);
    k_packPT<<<gP, 256, 0, stream>>>(preT, preP);

    hipMemsetAsync(e_acc, 0, (size_t)MAX_LEN * ENC * sizeof(float), stream);
    hipMemsetAsync(bar, 0, 2 * sizeof(int), stream);

    // encoder (after splitk: P0/P1 regions free)
    float* hid1 = buf4M;
    dim3 g1(N_TRAIN / 64, N_HID / 64);
    gemm_abT<true><<<g1, 256, 0, stream>>>(context, enc_w1, enc_b1, hid1,
                                           N_TRAIN, N_HID, N_FEAT, N_FEAT, N_FEAT, N_HID);
    dim3 g2(N_TRAIN / 64, ENC / 64);
    gemm_abT<false><<<g2, 256, 0, stream>>>(hid1, enc_w2, enc_b2, h,
                                            N_TRAIN, ENC, N_HID, N_HID, N_HID, ENC);

    // persistent fused loop
    k_loop<<<NB, 1024, 0, stream>>>(h, wpkT, rowsum, b_ih, b_hh, S, preP,
                                    WbT, att_b1, att_w2, att_b2, e_acc,
                                    scores, out, bar);
}

// Round 4
// 725.313 us; speedup vs baseline: 2.1870x; 2.1870x over previous
//
#include <hip/hip_runtime.h>
#include <hip/hip_bf16.h>
#include <math.h>

// Shapes
#define N_TRAIN 4096
#define N_FEAT  64
#define N_HID   256
#define ENC     256
#define N_ANTES 2048
#define ATT_H   256
#define MAX_LEN 16

typedef unsigned int u32;
typedef unsigned short u16;
typedef short short8 __attribute__((ext_vector_type(8)));
typedef float floatx16 __attribute__((ext_vector_type(16)));

__device__ __forceinline__ float fsig(float x)  { return 1.f / (1.f + __expf(-x)); }
__device__ __forceinline__ float ftanh(float x) { return 2.f / (1.f + __expf(-2.f * x)) - 1.f; }

// bf16 round-to-nearest-even helpers
__device__ __forceinline__ u16 f2bf(float x) {
    u32 b = __float_as_uint(x);
    return (u16)((b + 0x7FFFu + ((b >> 16) & 1u)) >> 16);
}
__device__ __forceinline__ float bf2f(u16 h) {
    return __uint_as_float(((u32)h) << 16);
}

// A/B fragment k-offset for v_mfma_f32_32x32x16_bf16 (2xK stacked CDNA layout):
// lane l, elem j (0..7) -> k = 4*(l>>5) + (j&3) + 8*(j>>2)
__device__ __forceinline__ int kin_of(int l, int j) {
    return ((l >> 5) << 2) + (j & 3) + ((j >> 2) << 3);
}

// ---------------------------------------------------------------------------
// Tiled GEMM: C[m,n] = act(bias[n] + sum_k A[m,k] * B[n,k]); 64x64x16 tiles.
// ---------------------------------------------------------------------------
template <bool RELU>
__global__ __launch_bounds__(256) void gemm_abT(
    const float* __restrict__ A, const float* __restrict__ B,
    const float* __restrict__ bias, float* __restrict__ C,
    int M, int N, int K, int lda, int ldb, int ldc)
{
    __shared__ __align__(16) float As[16][68];
    __shared__ __align__(16) float Bs[16][68];
    const int tid = threadIdx.x;
    const int m0 = blockIdx.x * 64, n0 = blockIdx.y * 64;
    const int tx = tid & 15, ty = tid >> 4;
    const int kl = tid & 15, rl = tid >> 4;
    float acc[4][4] = {};

    for (int k0 = 0; k0 < K; k0 += 16) {
        #pragma unroll
        for (int pp = 0; pp < 4; ++pp) {
            int r = rl + pp * 16;
            As[kl][r] = A[(size_t)(m0 + r) * lda + k0 + kl];
            Bs[kl][r] = B[(size_t)(n0 + r) * ldb + k0 + kl];
        }
        __syncthreads();
        #pragma unroll
        for (int k = 0; k < 16; ++k) {
            float4 av = *(const float4*)&As[k][ty * 4];
            float4 bv = *(const float4*)&Bs[k][tx * 4];
            float a4[4] = {av.x, av.y, av.z, av.w};
            float b4[4] = {bv.x, bv.y, bv.z, bv.w};
            #pragma unroll
            for (int i = 0; i < 4; ++i)
                #pragma unroll
                for (int j = 0; j < 4; ++j)
                    acc[i][j] = fmaf(a4[i], b4[j], acc[i][j]);
        }
        __syncthreads();
    }
    #pragma unroll
    for (int i = 0; i < 4; ++i) {
        int m = m0 + ty * 4 + i;
        #pragma unroll
        for (int j = 0; j < 4; ++j) {
            int n = n0 + tx * 4 + j;
            float v = acc[i][j] + bias[n];
            if (RELU) v = fmaxf(v, 0.f);
            C[(size_t)m * ldc + n] = v;
        }
    }
}

// ---------------------------------------------------------------------------
// Split-K GEMM, KSPLIT=8 partials into P0(4)/P1(2)/P2(2). Grid (M/64,N/64,8).
// ---------------------------------------------------------------------------
#define KSPLIT 8
__global__ __launch_bounds__(256) void gemm_ab_splitk(
    const float* __restrict__ A, const float* __restrict__ B,
    float* __restrict__ P0, float* __restrict__ P1, float* __restrict__ P2,
    int M, int N, int K, int lda, int ldb, int ldc)
{
    __shared__ __align__(16) float As[16][68];
    __shared__ __align__(16) float Bs[16][64];
    const int tid = threadIdx.x;
    const int m0 = blockIdx.x * 64, n0 = blockIdx.y * 64;
    const int kchunk = K / KSPLIT;
    const int kbeg = blockIdx.z * kchunk, kend = kbeg + kchunk;
    const int tx = tid & 15, ty = tid >> 4;
    const int kl = tid & 15, rl = tid >> 4;
    const int kb = tid >> 6, nb = tid & 63;
    float acc[4][4] = {};

    for (int k0 = kbeg; k0 < kend; k0 += 16) {
        #pragma unroll
        for (int pp = 0; pp < 4; ++pp) {
            As[kl][rl + pp * 16] = A[(size_t)(m0 + rl + pp * 16) * lda + k0 + kl];
            Bs[kb + pp * 4][nb]  = B[(size_t)(k0 + kb + pp * 4) * ldb + n0 + nb];
        }
        __syncthreads();
        #pragma unroll
        for (int k = 0; k < 16; ++k) {
            float4 av = *(const float4*)&As[k][ty * 4];
            float4 bv = *(const float4*)&Bs[k][tx * 4];
            float a4[4] = {av.x, av.y, av.z, av.w};
            float b4[4] = {bv.x, bv.y, bv.z, bv.w};
            #pragma unroll
            for (int i = 0; i < 4; ++i)
                #pragma unroll
                for (int j = 0; j < 4; ++j)
                    acc[i][j] = fmaf(a4[i], b4[j], acc[i][j]);
        }
        __syncthreads();
    }
    const int SZ = ATT_H * N_ANTES;
    const int bz = blockIdx.z;
    float* Cp = (bz < 4) ? P0 + (size_t)bz * SZ
              : (bz < 6) ? P1 + (size_t)(bz - 4) * SZ
                         : P2 + (size_t)(bz - 6) * SZ;
    #pragma unroll
    for (int i = 0; i < 4; ++i)
        #pragma unroll
        for (int j = 0; j < 4; ++j)
            Cp[(size_t)(m0 + ty * 4 + i) * ldc + n0 + tx * 4 + j] = acc[i][j];
}

__global__ __launch_bounds__(256) void k_reduce(
    const float* __restrict__ P0, const float* __restrict__ P1,
    const float* __restrict__ P2, float* __restrict__ preT)
{
    int gid = blockIdx.x * 256 + threadIdx.x;
    const int SZ = ATT_H * N_ANTES;
    float s = ((P0[gid] + P0[gid + SZ]) + (P0[gid + 2 * SZ] + P0[gid + 3 * SZ]))
            + ((P1[gid] + P1[gid + SZ]) + (P2[gid] + P2[gid + SZ]));
    preT[gid] = s;
}

// ---------------------------------------------------------------------------
// rowsum[j] = sum_k w_ih[j, k]
// ---------------------------------------------------------------------------
__global__ __launch_bounds__(256) void k_rowsum(const float* __restrict__ w_ih,
                                                float* __restrict__ rowsum)
{
    __shared__ float red[256];
    const int j = blockIdx.x, tid = threadIdx.x;
    float s = 0.f;
    for (int i = tid; i < N_ANTES; i += 256) s += w_ih[(size_t)j * N_ANTES + i];
    red[tid] = s; __syncthreads();
    for (int off = 128; off > 0; off >>= 1) {
        if (tid < off) red[tid] += red[tid + off];
        __syncthreads();
    }
    if (tid == 0) rowsum[j] = red[0];
}

// ---------------------------------------------------------------------------
// WbT[k*256 + j] = att_w1[j*(N_TRAIN+ENC) + N_TRAIN + k]
// ---------------------------------------------------------------------------
__global__ __launch_bounds__(256) void k_wbT(const float* __restrict__ att_w1,
                                             float* __restrict__ WbT)
{
    int gid = blockIdx.x * 256 + threadIdx.x;  // 0..65535
    int j = gid >> 8, k = gid & 255;
    WbT[(size_t)k * 256 + j] = att_w1[(size_t)j * (N_TRAIN + ENC) + N_TRAIN + k];
}

// ---------------------------------------------------------------------------
// Pack w_hh into B-fragment order (bf16 hi/lo), gate-interleaved columns.
// Column packing: block cb (0..15) owns 64 cols c: jj = cb*16 + (c>>2),
// gate g = c&3, global gate-col J = g*256 + jj.
// Wf[((cb*2+nsub)*16 + kt)*512 + lane*8 + j] = bf16(w_hh[J][k]),
//   k = kt*16 + kin(lane,j), c = nsub*32 + (lane&31).
// ---------------------------------------------------------------------------
__global__ __launch_bounds__(256) void k_packWf(const float* __restrict__ w_hh,
                                                u16* __restrict__ Wf_hi,
                                                u16* __restrict__ Wf_lo)
{
    int gid = blockIdx.x * 256 + threadIdx.x;      // 0..262143
    int j    = gid & 7;
    int l    = (gid >> 3) & 63;
    int kt   = (gid >> 9) & 15;
    int nsub = (gid >> 13) & 1;
    int cb   = gid >> 14;
    int k  = kt * 16 + kin_of(l, j);
    int cc = nsub * 32 + (l & 31);
    int jj = cb * 16 + (cc >> 2);
    int g  = cc & 3;
    int J  = g * 256 + jj;
    float v = w_hh[(size_t)J * 256 + k];
    u16 hi = f2bf(v);
    Wf_hi[gid] = hi;
    Wf_lo[gid] = f2bf(v - bf2f(hi));
}

// ---------------------------------------------------------------------------
// Pack fp32 h into A-fragment order (bf16 hi/lo).
// Hf[((mt*16 + kt)*64 + lane)*8 + j] = bf16(h[m][k]),
//   m = mt*32 + (lane&31), k = kt*16 + kin(lane,j).
// ---------------------------------------------------------------------------
__global__ __launch_bounds__(256) void k_packHf(const float* __restrict__ h,
                                                u16* __restrict__ Hf_hi,
                                                u16* __restrict__ Hf_lo)
{
    int gid = blockIdx.x * 256 + threadIdx.x;      // 0..1048575
    int j  = gid & 7;
    int l  = (gid >> 3) & 63;
    int kt = (gid >> 9) & 15;
    int mt = gid >> 13;
    int m = mt * 32 + (l & 31);
    int k = kt * 16 + kin_of(l, j);
    float v = h[(size_t)m * 256 + k];
    u16 hi = f2bf(v);
    Hf_hi[gid] = hi;
    Hf_lo[gid] = f2bf(v - bf2f(hi));
}

// ---------------------------------------------------------------------------
// Fused LSTM step via MFMA (bf16x3): grid (32 rb, 16 cb), 256 threads.
// Block computes z-tile 128 rows x 64 gate-interleaved cols:
//   wave msub=tid>>6 does a 32-row stripe (2 n-subtiles of 32), K=256.
//   3 MFMA passes: hi*hi + hi*lo + lo*hi  (~1e-4 rel accuracy).
// C frags -> z_lds[128][68] -> fused gate update (c fp32 global round-trip),
// h written straight back in A-fragment bf16 hi/lo order (ping-pong buffer),
// block e-partials reduced in LDS then one atomicAdd per enc-col.
// ---------------------------------------------------------------------------
__global__ __launch_bounds__(256) void k_zgemm(
    const u16* __restrict__ Hf_hi_r, const u16* __restrict__ Hf_lo_r,
    u16* __restrict__ Hf_hi_w, u16* __restrict__ Hf_lo_w,
    const u16* __restrict__ Wf_hi, const u16* __restrict__ Wf_lo,
    float* __restrict__ c,
    const float* __restrict__ rowsum, const float* __restrict__ b_ih,
    const float* __restrict__ b_hh, const float* __restrict__ S,
    const int* __restrict__ idx_buf, int t, float* __restrict__ e_acc_t)
{
    __shared__ __align__(16) float z_lds[128][68];
    __shared__ float red[256];
    const int tid  = threadIdx.x;
    const int lane = tid & 63;
    const int msub = tid >> 6;
    const int rb = blockIdx.x;       // 0..31  (128 rows each)
    const int cb = blockIdx.y;       // 0..15  (64 packed cols each)
    const int mt = rb * 4 + msub;

    floatx16 acc0 = {0,0,0,0,0,0,0,0,0,0,0,0,0,0,0,0};
    floatx16 acc1 = {0,0,0,0,0,0,0,0,0,0,0,0,0,0,0,0};
    const size_t aoff  = (size_t)mt * 16 * 512 + lane * 8;
    const size_t boff0 = (size_t)(cb * 2 + 0) * 16 * 512 + lane * 8;
    const size_t boff1 = (size_t)(cb * 2 + 1) * 16 * 512 + lane * 8;

    #pragma unroll 4
    for (int kt = 0; kt < 16; ++kt) {
        short8 ahi = *(const short8*)(Hf_hi_r + aoff  + kt * 512);
        short8 alo = *(const short8*)(Hf_lo_r + aoff  + kt * 512);
        short8 b0h = *(const short8*)(Wf_hi   + boff0 + kt * 512);
        short8 b0l = *(const short8*)(Wf_lo   + boff0 + kt * 512);
        short8 b1h = *(const short8*)(Wf_hi   + boff1 + kt * 512);
        short8 b1l = *(const short8*)(Wf_lo   + boff1 + kt * 512);
        acc0 = __builtin_amdgcn_mfma_f32_32x32x16_bf16(ahi, b0h, acc0, 0, 0, 0);
        acc0 = __builtin_amdgcn_mfma_f32_32x32x16_bf16(ahi, b0l, acc0, 0, 0, 0);
        acc0 = __builtin_amdgcn_mfma_f32_32x32x16_bf16(alo, b0h, acc0, 0, 0, 0);
        acc1 = __builtin_amdgcn_mfma_f32_32x32x16_bf16(ahi, b1h, acc1, 0, 0, 0);
        acc1 = __builtin_amdgcn_mfma_f32_32x32x16_bf16(ahi, b1l, acc1, 0, 0, 0);
        acc1 = __builtin_amdgcn_mfma_f32_32x32x16_bf16(alo, b1h, acc1, 0, 0, 0);
    }

    // C/D layout (HW-verified): col = lane&31, row = (q&3)+8*(q>>2)+4*(lane>>5)
    #pragma unroll
    for (int q = 0; q < 16; ++q) {
        int row = msub * 32 + (q & 3) + 8 * (q >> 2) + 4 * (lane >> 5);
        z_lds[row][lane & 31]        = acc0[q];
        z_lds[row][32 + (lane & 31)] = acc1[q];
    }
    __syncthreads();

    // ---- fused gates: thread = (jj_l, rg) handles 8 rows of one enc-col ----
    const int jj_l = tid & 15, rg = tid >> 4;
    const int Jc = cb * 16 + jj_l;           // enc-dim column (0..255)
    float rs[4], bs[4];
    #pragma unroll
    for (int g = 0; g < 4; ++g) {
        int J = g * 256 + Jc;
        rs[g] = rowsum[J];
        bs[g] = b_ih[J] + b_hh[J];
    }
    const int idxp = (t > 0) ? idx_buf[t - 1] : 0;
    float esum = 0.f;
    #pragma unroll
    for (int p = 0; p < 8; ++p) {
        int r = rg * 8 + p;
        int rglob = rb * 128 + r;
        float a = (t > 0) ? S[(size_t)rglob * N_ANTES + idxp] : 1.f;
        float4 z4 = *(const float4*)&z_lds[r][jj_l * 4];
        float zi = z4.x + fmaf(a, rs[0], bs[0]);
        float zf = z4.y + fmaf(a, rs[1], bs[1]);
        float zg = z4.z + fmaf(a, rs[2], bs[2]);
        float zo = z4.w + fmaf(a, rs[3], bs[3]);
        size_t coff = (size_t)rglob * 256 + Jc;
        float cn = fsig(zf) * c[coff] + fsig(zi) * ftanh(zg);
        float hn = fsig(zo) * ftanh(cn);
        c[coff] = cn;
        esum += hn;
        // write h back in A-fragment order (inverse of kin_of; bijective)
        u16 hi = f2bf(hn);
        u16 lo = f2bf(hn - bf2f(hi));
        int mtw    = rglob >> 5;
        int lane_a = (rglob & 31) + 32 * ((Jc >> 2) & 1);
        int ktw    = Jc >> 4;
        int jw     = (Jc & 3) + ((Jc >> 3) & 1) * 4;
        size_t off = (((size_t)mtw * 16 + ktw) * 64 + lane_a) * 8 + jw;
        Hf_hi_w[off] = hi;
        Hf_lo_w[off] = lo;
    }
    red[tid] = esum;
    __syncthreads();
    if (tid < 16) {
        float s = 0.f;
        #pragma unroll
        for (int q = 0; q < 16; ++q) s += red[tid + q * 16];
        atomicAdd(&e_acc_t[Jc - jj_l + tid], s);   // = e_acc_t[cb*16 + tid]
    }
}

// ---------------------------------------------------------------------------
// Fused attention: scores + log-softmax + argmax in ONE kernel (last-block).
// ---------------------------------------------------------------------------
__global__ __launch_bounds__(256) void k_att(
    const float* __restrict__ preT, const float* __restrict__ e_accum_t,
    const float* __restrict__ WbT, const float* __restrict__ att_b1,
    const float* __restrict__ att_w2, const float* __restrict__ att_b2,
    float* __restrict__ scores, float* __restrict__ out_t,
    int* __restrict__ idx_t, int* __restrict__ cnt)
{
    __shared__ float e_lds[256];
    __shared__ float u[256];
    __shared__ float w2s[256];
    __shared__ float red[256];
    const int tid = threadIdx.x;
    e_lds[tid] = e_accum_t[tid] * (1.f / (float)N_TRAIN);
    w2s[tid] = att_w2[tid];
    __syncthreads();

    float uacc = att_b1[tid];
    for (int k = 0; k < 256; ++k)
        uacc = fmaf(e_lds[k], WbT[(size_t)k * 256 + tid], uacc);
    u[tid] = uacc;
    __syncthreads();

    const int pl = tid & 31, jq = tid >> 5;   // 8-way j split
    const int p = blockIdx.x * 32 + pl;
    float sc = 0.f;
    #pragma unroll 4
    for (int j = jq; j < 256; j += 8) {
        float v = preT[(size_t)j * N_ANTES + p] + u[j];
        sc = fmaf(fmaxf(v, 0.f), w2s[j], sc);
    }
    red[tid] = sc;
    __syncthreads();
    if (tid < 32) {
        float s = att_b2[0];
        #pragma unroll
        for (int q = 0; q < 8; ++q) s += red[tid + q * 32];
        scores[blockIdx.x * 32 + tid] = s;
    }

    // ---- last-block handshake ----
    __threadfence();
    __syncthreads();
    __shared__ int is_last;
    if (tid == 0)
        is_last = (atomicAdd(cnt, 1) == (int)gridDim.x - 1);
    __syncthreads();
    if (!is_last) return;
    __threadfence();

    // ---- phase 2: log-softmax + argmax over 2048 scores (one block) ----
    __shared__ float smax[256];
    __shared__ int   sidx[256];
    __shared__ float ssum[256];

    float sv[8];
    #pragma unroll
    for (int i = 0; i < 8; ++i) sv[i] = scores[tid * 8 + i];

    float lmax = -INFINITY; int lidx = 0;
    #pragma unroll
    for (int i = 0; i < 8; ++i)
        if (sv[i] > lmax) { lmax = sv[i]; lidx = tid * 8 + i; }
    smax[tid] = lmax; sidx[tid] = lidx;
    __syncthreads();
    for (int off = 128; off > 0; off >>= 1) {
        if (tid < off) {
            float ov = smax[tid + off]; int oi = sidx[tid + off];
            if (ov > smax[tid] || (ov == smax[tid] && oi < sidx[tid])) {
                smax[tid] = ov; sidx[tid] = oi;
            }
        }
        __syncthreads();
    }
    const float gmax = smax[0];
    const int gidx = sidx[0];

    float lsum = 0.f;
    #pragma unroll
    for (int i = 0; i < 8; ++i) lsum += __expf(sv[i] - gmax);
    ssum[tid] = lsum;
    __syncthreads();
    for (int off = 128; off > 0; off >>= 1) {
        if (tid < off) ssum[tid] += ssum[tid + off];
        __syncthreads();
    }
    const float lse = gmax + logf(ssum[0]);

    #pragma unroll
    for (int i = 0; i < 8; ++i)
        out_t[tid * 8 + i] = sv[i] - lse;
    if (tid == 0) {
        idx_t[0] = gidx;
        *cnt = 0;
    }
}

// ---------------------------------------------------------------------------
extern "C" void kernel_launch(void* const* d_in, const int* in_sizes, int n_in,
                              void* d_out, int out_size, void* d_ws, size_t ws_size,
                              hipStream_t stream)
{
    (void)in_sizes; (void)n_in; (void)out_size; (void)ws_size;
    const float* context = (const float*)d_in[0];
    const float* S       = (const float*)d_in[1];
    const float* enc_w1  = (const float*)d_in[2];
    const float* enc_b1  = (const float*)d_in[3];
    const float* enc_w2  = (const float*)d_in[4];
    const float* enc_b2  = (const float*)d_in[5];
    const float* w_ih    = (const float*)d_in[6];
    const float* w_hh    = (const float*)d_in[7];
    const float* b_ih    = (const float*)d_in[8];
    const float* b_hh    = (const float*)d_in[9];
    const float* att_w1  = (const float*)d_in[10];
    const float* att_b1  = (const float*)d_in[11];
    const float* att_w2  = (const float*)d_in[12];
    const float* att_b2  = (const float*)d_in[13];
    float* out = (float*)d_out;
    float* ws  = (float*)d_ws;

    // ws layout (float offsets), extent unchanged (<= 5,057,552 floats):
    // [0 .. 2097152)      splitk P0 (x4) -> later h_fp32 @0 (1M), then Hf buf1
    // [1048576 .. 2097152) c (fp32, after P0 dead)
    // [2097152 .. 3145728) splitk P1 / hid1 -> later Hf buf0
    // [3145728 .. 3670016) preT
    // [3670016 .. 4718592) splitk P2 -> later Wf_hi/Wf_lo
    // [4718592 ..)         cnt; tail: rowsum/e_acc/scores/WbT/idxbuf
    float* h_fp32 = ws;                         // 1,048,576 (after splitk)
    float* c      = ws + 1048576;               // 1,048,576
    float* hid1   = ws + 2097152;               // 1,048,576
    float* preT   = ws + 3145728;               // 524,288
    float* P2     = ws + 3670016;               // 1,048,576
    u16* Hf_hi1 = (u16*)(ws + 0);               // 1M u16
    u16* Hf_lo1 = (u16*)(ws + 524288);
    u16* Hf_hi0 = (u16*)(ws + 2097152);
    u16* Hf_lo0 = (u16*)(ws + 2621440);
    u16* Wf_hi  = (u16*)(ws + 3670016);         // 262,144 u16
    u16* Wf_lo  = (u16*)(ws + 3801088);
    int*   cnt    = (int*)(ws + 4718592);
    float* rowsum = ws + 4984832;               // 1,024
    float* e_acc  = ws + 4985856;               // 4,096
    float* scores = ws + 4989952;               // 2,048
    float* WbT    = ws + 4992000;               // 65,536
    int*   idxbuf = (int*)(ws + 5057536);       // 16

    k_rowsum<<<1024, 256, 0, stream>>>(w_ih, rowsum);
    k_wbT<<<256, 256, 0, stream>>>(att_w1, WbT);

    // preT = Wa @ S (8 partials borrow P0=ws[0..2M), P1=hid1, P2)
    dim3 g3(ATT_H / 64, N_ANTES / 64, KSPLIT);
    gemm_ab_splitk<<<g3, 256, 0, stream>>>(att_w1, S, ws, hid1, P2,
                                           ATT_H, N_ANTES, N_TRAIN,
                                           N_TRAIN + ENC, N_ANTES, N_ANTES);
    k_reduce<<<(ATT_H * N_ANTES) / 256, 256, 0, stream>>>(ws, hid1, P2, preT);

    // partial buffers now dead: pack W, clear state
    k_packWf<<<1024, 256, 0, stream>>>(w_hh, Wf_hi, Wf_lo);
    hipMemsetAsync(c, 0, (size_t)N_TRAIN * ENC * sizeof(float), stream);
    hipMemsetAsync(e_acc, 0, (size_t)MAX_LEN * ENC * sizeof(float), stream);
    hipMemsetAsync(cnt, 0, sizeof(int), stream);

    // encoder
    dim3 g1(N_TRAIN / 64, N_HID / 64);
    gemm_abT<true><<<g1, 256, 0, stream>>>(context, enc_w1, enc_b1, hid1,
                                           N_TRAIN, N_HID, N_FEAT, N_FEAT, N_FEAT, N_HID);
    dim3 g2(N_TRAIN / 64, ENC / 64);
    gemm_abT<false><<<g2, 256, 0, stream>>>(hid1, enc_w2, enc_b2, h_fp32,
                                            N_TRAIN, ENC, N_HID, N_HID, N_HID, ENC);
    // pack h0 fragments (overwrites hid1, dead after gemm2)
    k_packHf<<<4096, 256, 0, stream>>>(h_fp32, Hf_hi0, Hf_lo0);

    dim3 gz(32, 16);
    for (int t = 0; t < MAX_LEN; ++t) {
        const u16 *hr, *lr; u16 *hw, *lw;
        if ((t & 1) == 0) { hr = Hf_hi0; lr = Hf_lo0; hw = Hf_hi1; lw = Hf_lo1; }
        else              { hr = Hf_hi1; lr = Hf_lo1; hw = Hf_hi0; lw = Hf_lo0; }
        k_zgemm<<<gz, 256, 0, stream>>>(hr, lr, hw, lw, Wf_hi, Wf_lo, c,
                                        rowsum, b_ih, b_hh, S, idxbuf, t,
                                        e_acc + t * 256);
        k_att<<<N_ANTES / 32, 256, 0, stream>>>(preT, e_acc + t * 256, WbT,
                                                att_b1, att_w2, att_b2, scores,
                                                out + t * N_ANTES, idxbuf + t, cnt);
    }
}

// Round 5
// 723.045 us; speedup vs baseline: 2.1939x; 1.0031x over previous
//
#include <hip/hip_runtime.h>
#include <hip/hip_bf16.h>
#include <math.h>

// Shapes
#define N_TRAIN 4096
#define N_FEAT  64
#define N_HID   256
#define ENC     256
#define N_ANTES 2048
#define ATT_H   256
#define MAX_LEN 16

typedef unsigned int u32;
typedef unsigned short u16;
typedef short short8 __attribute__((ext_vector_type(8)));
typedef float floatx16 __attribute__((ext_vector_type(16)));

__device__ __forceinline__ float fsig(float x)  { return 1.f / (1.f + __expf(-x)); }
__device__ __forceinline__ float ftanh(float x) { return 2.f / (1.f + __expf(-2.f * x)) - 1.f; }

// bf16 round-to-nearest-even helpers (validated R4 path for W/H)
__device__ __forceinline__ u16 f2bf(float x) {
    u32 b = __float_as_uint(x);
    return (u16)((b + 0x7FFFu + ((b >> 16) & 1u)) >> 16);
}
__device__ __forceinline__ float bf2f(u16 h) {
    return __uint_as_float(((u32)h) << 16);
}
// cheap truncation hi/lo split (4 VALU ops; residual v-hi is exact in fp32)
__device__ __forceinline__ void split_bf(float v, u16& hi, u16& lo) {
    u32 b = __float_as_uint(v);
    hi = (u16)(b >> 16);
    float r = v - __uint_as_float(b & 0xFFFF0000u);
    lo = (u16)(__float_as_uint(r) >> 16);
}

// A/B fragment k-offset for v_mfma_f32_32x32x16_bf16 (2xK stacked CDNA layout):
// lane l, elem j (0..7) -> k = 4*(l>>5) + (j&3) + 8*(j>>2)
__device__ __forceinline__ int kin_of(int l, int j) {
    return ((l >> 5) << 2) + (j & 3) + ((j >> 2) << 3);
}

// ---------------------------------------------------------------------------
// Tiled GEMM: C[m,n] = act(bias[n] + sum_k A[m,k] * B[n,k]); 64x64x16 tiles.
// (encoder only)
// ---------------------------------------------------------------------------
template <bool RELU>
__global__ __launch_bounds__(256) void gemm_abT(
    const float* __restrict__ A, const float* __restrict__ B,
    const float* __restrict__ bias, float* __restrict__ C,
    int M, int N, int K, int lda, int ldb, int ldc)
{
    __shared__ __align__(16) float As[16][68];
    __shared__ __align__(16) float Bs[16][68];
    const int tid = threadIdx.x;
    const int m0 = blockIdx.x * 64, n0 = blockIdx.y * 64;
    const int tx = tid & 15, ty = tid >> 4;
    const int kl = tid & 15, rl = tid >> 4;
    float acc[4][4] = {};

    for (int k0 = 0; k0 < K; k0 += 16) {
        #pragma unroll
        for (int pp = 0; pp < 4; ++pp) {
            int r = rl + pp * 16;
            As[kl][r] = A[(size_t)(m0 + r) * lda + k0 + kl];
            Bs[kl][r] = B[(size_t)(n0 + r) * ldb + k0 + kl];
        }
        __syncthreads();
        #pragma unroll
        for (int k = 0; k < 16; ++k) {
            float4 av = *(const float4*)&As[k][ty * 4];
            float4 bv = *(const float4*)&Bs[k][tx * 4];
            float a4[4] = {av.x, av.y, av.z, av.w};
            float b4[4] = {bv.x, bv.y, bv.z, bv.w};
            #pragma unroll
            for (int i = 0; i < 4; ++i)
                #pragma unroll
                for (int j = 0; j < 4; ++j)
                    acc[i][j] = fmaf(a4[i], b4[j], acc[i][j]);
        }
        __syncthreads();
    }
    #pragma unroll
    for (int i = 0; i < 4; ++i) {
        int m = m0 + ty * 4 + i;
        #pragma unroll
        for (int j = 0; j < 4; ++j) {
            int n = n0 + tx * 4 + j;
            float v = acc[i][j] + bias[n];
            if (RELU) v = fmaxf(v, 0.f);
            C[(size_t)m * ldc + n] = v;
        }
    }
}

// ---------------------------------------------------------------------------
// rowsum[j] = sum_k w_ih[j, k]
// ---------------------------------------------------------------------------
__global__ __launch_bounds__(256) void k_rowsum(const float* __restrict__ w_ih,
                                                float* __restrict__ rowsum)
{
    __shared__ float red[256];
    const int j = blockIdx.x, tid = threadIdx.x;
    float s = 0.f;
    for (int i = tid; i < N_ANTES; i += 256) s += w_ih[(size_t)j * N_ANTES + i];
    red[tid] = s; __syncthreads();
    for (int off = 128; off > 0; off >>= 1) {
        if (tid < off) red[tid] += red[tid + off];
        __syncthreads();
    }
    if (tid == 0) rowsum[j] = red[0];
}

// ---------------------------------------------------------------------------
// WbT[k*256 + j] = att_w1[j*(N_TRAIN+ENC) + N_TRAIN + k]
// ---------------------------------------------------------------------------
__global__ __launch_bounds__(256) void k_wbT(const float* __restrict__ att_w1,
                                             float* __restrict__ WbT)
{
    int gid = blockIdx.x * 256 + threadIdx.x;  // 0..65535
    int j = gid >> 8, k = gid & 255;
    WbT[(size_t)k * 256 + j] = att_w1[(size_t)j * (N_TRAIN + ENC) + N_TRAIN + k];
}

// ---------------------------------------------------------------------------
// Pack Wa = att_w1[:, :N_TRAIN] (256x4096) into A-fragment order (bf16 hi/lo).
// Af[((mt*256 + kt)*64 + l)*8 + j] = Wa[mt*32 + (l&31)][kt*16 + kin(l,j)]
// ---------------------------------------------------------------------------
__global__ __launch_bounds__(256) void k_packAf(const float* __restrict__ att_w1,
                                                u16* __restrict__ Af_hi,
                                                u16* __restrict__ Af_lo)
{
    int gid = blockIdx.x * 256 + threadIdx.x;   // 0..1048575
    int j  = gid & 7;
    int l  = (gid >> 3) & 63;
    int kt = (gid >> 9) & 255;
    int mt = gid >> 17;
    int m = mt * 32 + (l & 31);
    int k = kt * 16 + kin_of(l, j);
    float v = att_w1[(size_t)m * (N_TRAIN + ENC) + k];
    u16 hi, lo; split_bf(v, hi, lo);
    Af_hi[gid] = hi;
    Af_lo[gid] = lo;
}

// ---------------------------------------------------------------------------
// preT = Wa @ S via MFMA bf16x3, split-K=4. Grid (4 kz, 32 np), 256 thr.
// Block: full M=256 x 64 cols, K-chunk 1024. Wave w: rows w*64..w*64+63.
// A from packed frags; B (S) loaded fp32 coalesced + split in-flight.
// Partials fp32 -> P[kz] (reduced by k_reduce4).
// ---------------------------------------------------------------------------
#define PSPLIT 4
__global__ __launch_bounds__(256) void k_gemm_preT(
    const u16* __restrict__ Af_hi, const u16* __restrict__ Af_lo,
    const float* __restrict__ S, float* __restrict__ P)
{
    const int tid = threadIdx.x, lane = tid & 63, w = tid >> 6;
    const int kz = blockIdx.x;          // 0..3
    const int np = blockIdx.y;          // 0..31
    const int p0 = np * 64;
    const int nb = p0 + (lane & 31);
    const int kb = 4 * (lane >> 5);
    floatx16 acc[2][2] = {};

    const int kt_beg = kz * 64, kt_end = kt_beg + 64;
    #pragma unroll 2
    for (int kt = kt_beg; kt < kt_end; ++kt) {
        short8 ahi[2], alo[2], bhi[2], blo[2];
        #pragma unroll
        for (int mi = 0; mi < 2; ++mi) {
            size_t ao = (((size_t)(w * 2 + mi) * 256 + kt) * 64 + lane) * 8;
            ahi[mi] = *(const short8*)(Af_hi + ao);
            alo[mi] = *(const short8*)(Af_lo + ao);
        }
        #pragma unroll
        for (int ni = 0; ni < 2; ++ni) {
            #pragma unroll
            for (int j = 0; j < 8; ++j) {
                int k = kt * 16 + kb + (j & 3) + 8 * (j >> 2);
                float v = S[(size_t)k * N_ANTES + nb + ni * 32];
                u16 hi, lo; split_bf(v, hi, lo);
                bhi[ni][j] = (short)hi;
                blo[ni][j] = (short)lo;
            }
        }
        #pragma unroll
        for (int mi = 0; mi < 2; ++mi)
            #pragma unroll
            for (int ni = 0; ni < 2; ++ni) {
                acc[mi][ni] = __builtin_amdgcn_mfma_f32_32x32x16_bf16(
                    ahi[mi], bhi[ni], acc[mi][ni], 0, 0, 0);
                acc[mi][ni] = __builtin_amdgcn_mfma_f32_32x32x16_bf16(
                    ahi[mi], blo[ni], acc[mi][ni], 0, 0, 0);
                acc[mi][ni] = __builtin_amdgcn_mfma_f32_32x32x16_bf16(
                    alo[mi], bhi[ni], acc[mi][ni], 0, 0, 0);
            }
    }

    float* Pk = P + (size_t)kz * (ATT_H * N_ANTES);
    #pragma unroll
    for (int mi = 0; mi < 2; ++mi)
        #pragma unroll
        for (int ni = 0; ni < 2; ++ni)
            #pragma unroll
            for (int q = 0; q < 16; ++q) {
                int row = w * 64 + mi * 32 + (q & 3) + 8 * (q >> 2) + 4 * (lane >> 5);
                Pk[(size_t)row * N_ANTES + p0 + ni * 32 + (lane & 31)] = acc[mi][ni][q];
            }
}

__global__ __launch_bounds__(256) void k_reduce4(const float* __restrict__ P,
                                                 float* __restrict__ preT)
{
    int gid = blockIdx.x * 256 + threadIdx.x;
    const int SZ = ATT_H * N_ANTES;
    preT[gid] = (P[gid] + P[gid + SZ]) + (P[gid + 2 * SZ] + P[gid + 3 * SZ]);
}

// ---------------------------------------------------------------------------
// Pack w_hh into B-fragment order (bf16 hi/lo), gate-interleaved columns.
// ---------------------------------------------------------------------------
__global__ __launch_bounds__(256) void k_packWf(const float* __restrict__ w_hh,
                                                u16* __restrict__ Wf_hi,
                                                u16* __restrict__ Wf_lo)
{
    int gid = blockIdx.x * 256 + threadIdx.x;      // 0..262143
    int j    = gid & 7;
    int l    = (gid >> 3) & 63;
    int kt   = (gid >> 9) & 15;
    int nsub = (gid >> 13) & 1;
    int cb   = gid >> 14;
    int k  = kt * 16 + kin_of(l, j);
    int cc = nsub * 32 + (l & 31);
    int jj = cb * 16 + (cc >> 2);
    int g  = cc & 3;
    int J  = g * 256 + jj;
    float v = w_hh[(size_t)J * 256 + k];
    u16 hi = f2bf(v);
    Wf_hi[gid] = hi;
    Wf_lo[gid] = f2bf(v - bf2f(hi));
}

// ---------------------------------------------------------------------------
// Pack fp32 h into A-fragment order (bf16 hi/lo).
// ---------------------------------------------------------------------------
__global__ __launch_bounds__(256) void k_packHf(const float* __restrict__ h,
                                                u16* __restrict__ Hf_hi,
                                                u16* __restrict__ Hf_lo)
{
    int gid = blockIdx.x * 256 + threadIdx.x;      // 0..1048575
    int j  = gid & 7;
    int l  = (gid >> 3) & 63;
    int kt = (gid >> 9) & 15;
    int mt = gid >> 13;
    int m = mt * 32 + (l & 31);
    int k = kt * 16 + kin_of(l, j);
    float v = h[(size_t)m * 256 + k];
    u16 hi = f2bf(v);
    Hf_hi[gid] = hi;
    Hf_lo[gid] = f2bf(v - bf2f(hi));
}

// ---------------------------------------------------------------------------
// Fused LSTM step via MFMA (bf16x3): grid (32 rb, 16 cb), 256 threads.
// ---------------------------------------------------------------------------
__global__ __launch_bounds__(256) void k_zgemm(
    const u16* __restrict__ Hf_hi_r, const u16* __restrict__ Hf_lo_r,
    u16* __restrict__ Hf_hi_w, u16* __restrict__ Hf_lo_w,
    const u16* __restrict__ Wf_hi, const u16* __restrict__ Wf_lo,
    float* __restrict__ c,
    const float* __restrict__ rowsum, const float* __restrict__ b_ih,
    const float* __restrict__ b_hh, const float* __restrict__ S,
    const int* __restrict__ idx_buf, int t, float* __restrict__ e_acc_t)
{
    __shared__ __align__(16) float z_lds[128][68];
    __shared__ float red[256];
    const int tid  = threadIdx.x;
    const int lane = tid & 63;
    const int msub = tid >> 6;
    const int rb = blockIdx.x;       // 0..31  (128 rows each)
    const int cb = blockIdx.y;       // 0..15  (64 packed cols each)
    const int mt = rb * 4 + msub;

    floatx16 acc0 = {0,0,0,0,0,0,0,0,0,0,0,0,0,0,0,0};
    floatx16 acc1 = {0,0,0,0,0,0,0,0,0,0,0,0,0,0,0,0};
    const size_t aoff  = (size_t)mt * 16 * 512 + lane * 8;
    const size_t boff0 = (size_t)(cb * 2 + 0) * 16 * 512 + lane * 8;
    const size_t boff1 = (size_t)(cb * 2 + 1) * 16 * 512 + lane * 8;

    #pragma unroll 4
    for (int kt = 0; kt < 16; ++kt) {
        short8 ahi = *(const short8*)(Hf_hi_r + aoff  + kt * 512);
        short8 alo = *(const short8*)(Hf_lo_r + aoff  + kt * 512);
        short8 b0h = *(const short8*)(Wf_hi   + boff0 + kt * 512);
        short8 b0l = *(const short8*)(Wf_lo   + boff0 + kt * 512);
        short8 b1h = *(const short8*)(Wf_hi   + boff1 + kt * 512);
        short8 b1l = *(const short8*)(Wf_lo   + boff1 + kt * 512);
        acc0 = __builtin_amdgcn_mfma_f32_32x32x16_bf16(ahi, b0h, acc0, 0, 0, 0);
        acc0 = __builtin_amdgcn_mfma_f32_32x32x16_bf16(ahi, b0l, acc0, 0, 0, 0);
        acc0 = __builtin_amdgcn_mfma_f32_32x32x16_bf16(alo, b0h, acc0, 0, 0, 0);
        acc1 = __builtin_amdgcn_mfma_f32_32x32x16_bf16(ahi, b1h, acc1, 0, 0, 0);
        acc1 = __builtin_amdgcn_mfma_f32_32x32x16_bf16(ahi, b1l, acc1, 0, 0, 0);
        acc1 = __builtin_amdgcn_mfma_f32_32x32x16_bf16(alo, b1h, acc1, 0, 0, 0);
    }

    // C/D layout (HW-verified): col = lane&31, row = (q&3)+8*(q>>2)+4*(lane>>5)
    #pragma unroll
    for (int q = 0; q < 16; ++q) {
        int row = msub * 32 + (q & 3) + 8 * (q >> 2) + 4 * (lane >> 5);
        z_lds[row][lane & 31]        = acc0[q];
        z_lds[row][32 + (lane & 31)] = acc1[q];
    }
    __syncthreads();

    // ---- fused gates: thread = (jj_l, rg) handles 8 rows of one enc-col ----
    const int jj_l = tid & 15, rg = tid >> 4;
    const int Jc = cb * 16 + jj_l;           // enc-dim column (0..255)
    float rs[4], bs[4];
    #pragma unroll
    for (int g = 0; g < 4; ++g) {
        int J = g * 256 + Jc;
        rs[g] = rowsum[J];
        bs[g] = b_ih[J] + b_hh[J];
    }
    const int idxp = (t > 0) ? idx_buf[t - 1] : 0;
    float esum = 0.f;
    #pragma unroll
    for (int p = 0; p < 8; ++p) {
        int r = rg * 8 + p;
        int rglob = rb * 128 + r;
        float a = (t > 0) ? S[(size_t)rglob * N_ANTES + idxp] : 1.f;
        float4 z4 = *(const float4*)&z_lds[r][jj_l * 4];
        float zi = z4.x + fmaf(a, rs[0], bs[0]);
        float zf = z4.y + fmaf(a, rs[1], bs[1]);
        float zg = z4.z + fmaf(a, rs[2], bs[2]);
        float zo = z4.w + fmaf(a, rs[3], bs[3]);
        size_t coff = (size_t)rglob * 256 + Jc;
        float cn = fsig(zf) * c[coff] + fsig(zi) * ftanh(zg);
        float hn = fsig(zo) * ftanh(cn);
        c[coff] = cn;
        esum += hn;
        // write h back in A-fragment order (inverse of kin_of; bijective)
        u16 hi = f2bf(hn);
        u16 lo = f2bf(hn - bf2f(hi));
        int mtw    = rglob >> 5;
        int lane_a = (rglob & 31) + 32 * ((Jc >> 2) & 1);
        int ktw    = Jc >> 4;
        int jw     = (Jc & 3) + ((Jc >> 3) & 1) * 4;
        size_t off = (((size_t)mtw * 16 + ktw) * 64 + lane_a) * 8 + jw;
        Hf_hi_w[off] = hi;
        Hf_lo_w[off] = lo;
    }
    red[tid] = esum;
    __syncthreads();
    if (tid < 16) {
        float s = 0.f;
        #pragma unroll
        for (int q = 0; q < 16; ++q) s += red[tid + q * 16];
        atomicAdd(&e_acc_t[Jc - jj_l + tid], s);   // = e_acc_t[cb*16 + tid]
    }
}

// ---------------------------------------------------------------------------
// Fused attention: scores + log-softmax + argmax in ONE kernel (last-block).
// ---------------------------------------------------------------------------
__global__ __launch_bounds__(256) void k_att(
    const float* __restrict__ preT, const float* __restrict__ e_accum_t,
    const float* __restrict__ WbT, const float* __restrict__ att_b1,
    const float* __restrict__ att_w2, const float* __restrict__ att_b2,
    float* __restrict__ scores, float* __restrict__ out_t,
    int* __restrict__ idx_t, int* __restrict__ cnt)
{
    __shared__ float e_lds[256];
    __shared__ float u[256];
    __shared__ float w2s[256];
    __shared__ float red[256];
    const int tid = threadIdx.x;
    e_lds[tid] = e_accum_t[tid] * (1.f / (float)N_TRAIN);
    w2s[tid] = att_w2[tid];
    __syncthreads();

    float uacc = att_b1[tid];
    for (int k = 0; k < 256; ++k)
        uacc = fmaf(e_lds[k], WbT[(size_t)k * 256 + tid], uacc);
    u[tid] = uacc;
    __syncthreads();

    const int pl = tid & 31, jq = tid >> 5;   // 8-way j split
    const int p = blockIdx.x * 32 + pl;
    float sc = 0.f;
    #pragma unroll 4
    for (int j = jq; j < 256; j += 8) {
        float v = preT[(size_t)j * N_ANTES + p] + u[j];
        sc = fmaf(fmaxf(v, 0.f), w2s[j], sc);
    }
    red[tid] = sc;
    __syncthreads();
    if (tid < 32) {
        float s = att_b2[0];
        #pragma unroll
        for (int q = 0; q < 8; ++q) s += red[tid + q * 32];
        scores[blockIdx.x * 32 + tid] = s;
    }

    // ---- last-block handshake ----
    __threadfence();
    __syncthreads();
    __shared__ int is_last;
    if (tid == 0)
        is_last = (atomicAdd(cnt, 1) == (int)gridDim.x - 1);
    __syncthreads();
    if (!is_last) return;
    __threadfence();

    // ---- phase 2: log-softmax + argmax over 2048 scores (one block) ----
    __shared__ float smax[256];
    __shared__ int   sidx[256];
    __shared__ float ssum[256];

    float sv[8];
    #pragma unroll
    for (int i = 0; i < 8; ++i) sv[i] = scores[tid * 8 + i];

    float lmax = -INFINITY; int lidx = 0;
    #pragma unroll
    for (int i = 0; i < 8; ++i)
        if (sv[i] > lmax) { lmax = sv[i]; lidx = tid * 8 + i; }
    smax[tid] = lmax; sidx[tid] = lidx;
    __syncthreads();
    for (int off = 128; off > 0; off >>= 1) {
        if (tid < off) {
            float ov = smax[tid + off]; int oi = sidx[tid + off];
            if (ov > smax[tid] || (ov == smax[tid] && oi < sidx[tid])) {
                smax[tid] = ov; sidx[tid] = oi;
            }
        }
        __syncthreads();
    }
    const float gmax = smax[0];
    const int gidx = sidx[0];

    float lsum = 0.f;
    #pragma unroll
    for (int i = 0; i < 8; ++i) lsum += __expf(sv[i] - gmax);
    ssum[tid] = lsum;
    __syncthreads();
    for (int off = 128; off > 0; off >>= 1) {
        if (tid < off) ssum[tid] += ssum[tid + off];
        __syncthreads();
    }
    const float lse = gmax + logf(ssum[0]);

    #pragma unroll
    for (int i = 0; i < 8; ++i)
        out_t[tid * 8 + i] = sv[i] - lse;
    if (tid == 0) {
        idx_t[0] = gidx;
        *cnt = 0;
    }
}

// ---------------------------------------------------------------------------
extern "C" void kernel_launch(void* const* d_in, const int* in_sizes, int n_in,
                              void* d_out, int out_size, void* d_ws, size_t ws_size,
                              hipStream_t stream)
{
    (void)in_sizes; (void)n_in; (void)out_size; (void)ws_size;
    const float* context = (const float*)d_in[0];
    const float* S       = (const float*)d_in[1];
    const float* enc_w1  = (const float*)d_in[2];
    const float* enc_b1  = (const float*)d_in[3];
    const float* enc_w2  = (const float*)d_in[4];
    const float* enc_b2  = (const float*)d_in[5];
    const float* w_ih    = (const float*)d_in[6];
    const float* w_hh    = (const float*)d_in[7];
    const float* b_ih    = (const float*)d_in[8];
    const float* b_hh    = (const float*)d_in[9];
    const float* att_w1  = (const float*)d_in[10];
    const float* att_b1  = (const float*)d_in[11];
    const float* att_w2  = (const float*)d_in[12];
    const float* att_b2  = (const float*)d_in[13];
    float* out = (float*)d_out;
    float* ws  = (float*)d_ws;

    // ws layout (float offsets), footprint unchanged (<= 5,057,552 floats):
    // phase A (preT):  P partials [0..2M), Af hi/lo in [2097152..3145728)
    // phase B (enc):   hid1 [2097152..3145728), h_fp32 [0..1M)
    // loop-resident:   Hf1 [0..1M), c [1M..2M), Hf0 [2097152..3145728),
    //                  preT [3145728..3670016), Wf [3670016..3932160),
    //                  tail: cnt/rowsum/e_acc/scores/WbT/idxbuf
    float* P      = ws;                         // 4 x 512K fp32 partials
    float* h_fp32 = ws;                         // (after P dead)
    float* c      = ws + 1048576;
    float* hid1   = ws + 2097152;
    float* preT   = ws + 3145728;
    u16* Af_hi  = (u16*)(ws + 2097152);         // 1M u16 (dead before gemm1)
    u16* Af_lo  = (u16*)(ws + 2621440);
    u16* Hf_hi1 = (u16*)(ws + 0);
    u16* Hf_lo1 = (u16*)(ws + 524288);
    u16* Hf_hi0 = (u16*)(ws + 2097152);
    u16* Hf_lo0 = (u16*)(ws + 2621440);
    u16* Wf_hi  = (u16*)(ws + 3670016);         // 262,144 u16
    u16* Wf_lo  = (u16*)(ws + 3801088);
    int*   cnt    = (int*)(ws + 4718592);
    float* rowsum = ws + 4984832;               // 1,024
    float* e_acc  = ws + 4985856;               // 4,096
    float* scores = ws + 4989952;               // 2,048
    float* WbT    = ws + 4992000;               // 65,536
    int*   idxbuf = (int*)(ws + 5057536);       // 16

    k_rowsum<<<1024, 256, 0, stream>>>(w_ih, rowsum);
    k_wbT<<<256, 256, 0, stream>>>(att_w1, WbT);
    k_packWf<<<1024, 256, 0, stream>>>(w_hh, Wf_hi, Wf_lo);

    // ---- preT = Wa @ S via MFMA bf16x3 split-K ----
    k_packAf<<<4096, 256, 0, stream>>>(att_w1, Af_hi, Af_lo);
    dim3 gp(PSPLIT, N_ANTES / 64);
    k_gemm_preT<<<gp, 256, 0, stream>>>(Af_hi, Af_lo, S, P);
    k_reduce4<<<(ATT_H * N_ANTES) / 256, 256, 0, stream>>>(P, preT);

    // P region dead now: clear state
    hipMemsetAsync(c, 0, (size_t)N_TRAIN * ENC * sizeof(float), stream);
    hipMemsetAsync(e_acc, 0, (size_t)MAX_LEN * ENC * sizeof(float), stream);
    hipMemsetAsync(cnt, 0, sizeof(int), stream);

    // ---- encoder (Af dead -> hid1 region reusable) ----
    dim3 g1(N_TRAIN / 64, N_HID / 64);
    gemm_abT<true><<<g1, 256, 0, stream>>>(context, enc_w1, enc_b1, hid1,
                                           N_TRAIN, N_HID, N_FEAT, N_FEAT, N_FEAT, N_HID);
    dim3 g2(N_TRAIN / 64, ENC / 64);
    gemm_abT<false><<<g2, 256, 0, stream>>>(hid1, enc_w2, enc_b2, h_fp32,
                                            N_TRAIN, ENC, N_HID, N_HID, N_HID, ENC);
    // pack h0 fragments (overwrites hid1, dead after gemm2)
    k_packHf<<<4096, 256, 0, stream>>>(h_fp32, Hf_hi0, Hf_lo0);

    dim3 gz(32, 16);
    for (int t = 0; t < MAX_LEN; ++t) {
        const u16 *hr, *lr; u16 *hw, *lw;
        if ((t & 1) == 0) { hr = Hf_hi0; lr = Hf_lo0; hw = Hf_hi1; lw = Hf_lo1; }
        else              { hr = Hf_hi1; lr = Hf_lo1; hw = Hf_hi0; lw = Hf_lo0; }
        k_zgemm<<<gz, 256, 0, stream>>>(hr, lr, hw, lw, Wf_hi, Wf_lo, c,
                                        rowsum, b_ih, b_hh, S, idxbuf, t,
                                        e_acc + t * 256);
        k_att<<<N_ANTES / 32, 256, 0, stream>>>(preT, e_acc + t * 256, WbT,
                                                att_b1, att_w2, att_b2, scores,
                                                out + t * N_ANTES, idxbuf + t, cnt);
    }
}

// Round 8
// 704.509 us; speedup vs baseline: 2.2516x; 1.0263x over previous
//
#include <hip/hip_runtime.h>
#include <hip/hip_bf16.h>
#include <math.h>

// Shapes
#define N_TRAIN 4096
#define N_FEAT  64
#define N_HID   256
#define ENC     256
#define N_ANTES 2048
#define ATT_H   256
#define MAX_LEN 16

typedef unsigned int u32;
typedef unsigned short u16;
typedef short short8 __attribute__((ext_vector_type(8)));
typedef float floatx16 __attribute__((ext_vector_type(16)));

__device__ __forceinline__ float fsig(float x)  { return 1.f / (1.f + __expf(-x)); }
__device__ __forceinline__ float ftanh(float x) { return 2.f / (1.f + __expf(-2.f * x)) - 1.f; }

// bf16 round-to-nearest-even helpers
__device__ __forceinline__ u16 f2bf(float x) {
    u32 b = __float_as_uint(x);
    return (u16)((b + 0x7FFFu + ((b >> 16) & 1u)) >> 16);
}
__device__ __forceinline__ float bf2f(u16 h) {
    return __uint_as_float(((u32)h) << 16);
}
// cheap truncation hi/lo split (residual v-hi exact in fp32)
__device__ __forceinline__ void split_bf(float v, u16& hi, u16& lo) {
    u32 b = __float_as_uint(v);
    hi = (u16)(b >> 16);
    float r = v - __uint_as_float(b & 0xFFFF0000u);
    lo = (u16)(__float_as_uint(r) >> 16);
}

// A/B fragment k-offset for v_mfma_f32_32x32x16_bf16 (2xK stacked CDNA layout):
// lane l, elem j (0..7) -> k = 4*(l>>5) + (j&3) + 8*(j>>2)
__device__ __forceinline__ int kin_of(int l, int j) {
    return ((l >> 5) << 2) + (j & 3) + ((j >> 2) << 3);
}

// ---------------------------------------------------------------------------
// Tiled GEMM: C[m,n] = act(bias[n] + sum_k A[m,k] * B[n,k]); 64x64x16 tiles.
// (encoder only)
// ---------------------------------------------------------------------------
template <bool RELU>
__global__ __launch_bounds__(256) void gemm_abT(
    const float* __restrict__ A, const float* __restrict__ B,
    const float* __restrict__ bias, float* __restrict__ C,
    int M, int N, int K, int lda, int ldb, int ldc)
{
    __shared__ __align__(16) float As[16][68];
    __shared__ __align__(16) float Bs[16][68];
    const int tid = threadIdx.x;
    const int m0 = blockIdx.x * 64, n0 = blockIdx.y * 64;
    const int tx = tid & 15, ty = tid >> 4;
    const int kl = tid & 15, rl = tid >> 4;
    float acc[4][4] = {};

    for (int k0 = 0; k0 < K; k0 += 16) {
        #pragma unroll
        for (int pp = 0; pp < 4; ++pp) {
            int r = rl + pp * 16;
            As[kl][r] = A[(size_t)(m0 + r) * lda + k0 + kl];
            Bs[kl][r] = B[(size_t)(n0 + r) * ldb + k0 + kl];
        }
        __syncthreads();
        #pragma unroll
        for (int k = 0; k < 16; ++k) {
            float4 av = *(const float4*)&As[k][ty * 4];
            float4 bv = *(const float4*)&Bs[k][tx * 4];
            float a4[4] = {av.x, av.y, av.z, av.w};
            float b4[4] = {bv.x, bv.y, bv.z, bv.w};
            #pragma unroll
            for (int i = 0; i < 4; ++i)
                #pragma unroll
                for (int j = 0; j < 4; ++j)
                    acc[i][j] = fmaf(a4[i], b4[j], acc[i][j]);
        }
        __syncthreads();
    }
    #pragma unroll
    for (int i = 0; i < 4; ++i) {
        int m = m0 + ty * 4 + i;
        #pragma unroll
        for (int j = 0; j < 4; ++j) {
            int n = n0 + tx * 4 + j;
            float v = acc[i][j] + bias[n];
            if (RELU) v = fmaxf(v, 0.f);
            C[(size_t)m * ldc + n] = v;
        }
    }
}

// ---------------------------------------------------------------------------
// rowsum[j] = sum_k w_ih[j, k]
// ---------------------------------------------------------------------------
__global__ __launch_bounds__(256) void k_rowsum(const float* __restrict__ w_ih,
                                                float* __restrict__ rowsum)
{
    __shared__ float red[256];
    const int j = blockIdx.x, tid = threadIdx.x;
    float s = 0.f;
    for (int i = tid; i < N_ANTES; i += 256) s += w_ih[(size_t)j * N_ANTES + i];
    red[tid] = s; __syncthreads();
    for (int off = 128; off > 0; off >>= 1) {
        if (tid < off) red[tid] += red[tid + off];
        __syncthreads();
    }
    if (tid == 0) rowsum[j] = red[0];
}

// ---------------------------------------------------------------------------
// WbT[k*256 + j] = att_w1[j*(N_TRAIN+ENC) + N_TRAIN + k]
// ---------------------------------------------------------------------------
__global__ __launch_bounds__(256) void k_wbT(const float* __restrict__ att_w1,
                                             float* __restrict__ WbT)
{
    int gid = blockIdx.x * 256 + threadIdx.x;  // 0..65535
    int j = gid >> 8, k = gid & 255;
    WbT[(size_t)k * 256 + j] = att_w1[(size_t)j * (N_TRAIN + ENC) + N_TRAIN + k];
}

// ---------------------------------------------------------------------------
// Pack Wa = att_w1[:, :N_TRAIN] (256x4096) into A-fragment order (bf16 hi/lo).
// Af[((mt*256 + kt)*64 + l)*8 + j] = Wa[mt*32 + (l&31)][kt*16 + kin(l,j)]
// ---------------------------------------------------------------------------
__global__ __launch_bounds__(256) void k_packAf(const float* __restrict__ att_w1,
                                                u16* __restrict__ Af_hi,
                                                u16* __restrict__ Af_lo)
{
    int gid = blockIdx.x * 256 + threadIdx.x;   // 0..1048575
    int j  = gid & 7;
    int l  = (gid >> 3) & 63;
    int kt = (gid >> 9) & 255;
    int mt = gid >> 17;
    int m = mt * 32 + (l & 31);
    int k = kt * 16 + kin_of(l, j);
    float v = att_w1[(size_t)m * (N_TRAIN + ENC) + k];
    u16 hi, lo; split_bf(v, hi, lo);
    Af_hi[gid] = hi;
    Af_lo[gid] = lo;
}

// ---------------------------------------------------------------------------
// preT = Wa @ S via MFMA bf16x3, split-K=4. Grid (4 kz, 32 np, 4 mq), 256 thr.
// ONE 32x32 output job per wave: wave w -> mt = mq*2+(w&1), ni = w>>1.
// 2048 waves total vs R5's 512 -- fixes the 5%-occupancy latency exposure.
// ---------------------------------------------------------------------------
#define PSPLIT 4
__global__ __launch_bounds__(256) void k_gemm_preT(
    const u16* __restrict__ Af_hi, const u16* __restrict__ Af_lo,
    const float* __restrict__ S, float* __restrict__ P)
{
    const int tid = threadIdx.x, lane = tid & 63, w = tid >> 6;
    const int kz = blockIdx.x;          // 0..3
    const int np = blockIdx.y;          // 0..31
    const int mq = blockIdx.z;          // 0..3
    const int mt = mq * 2 + (w & 1);    // 0..7
    const int ni = w >> 1;              // 0..1
    const int nb = np * 64 + ni * 32 + (lane & 31);
    const int kb = 4 * (lane >> 5);
    floatx16 acc = {0,0,0,0,0,0,0,0,0,0,0,0,0,0,0,0};

    const int kt_beg = kz * 64, kt_end = kt_beg + 64;
    #pragma unroll 4
    for (int kt = kt_beg; kt < kt_end; ++kt) {
        size_t ao = (((size_t)mt * 256 + kt) * 64 + lane) * 8;
        short8 ahi = *(const short8*)(Af_hi + ao);
        short8 alo = *(const short8*)(Af_lo + ao);
        short8 bhi, blo;
        #pragma unroll
        for (int j = 0; j < 8; ++j) {
            int k = kt * 16 + kb + (j & 3) + 8 * (j >> 2);
            float v = S[(size_t)k * N_ANTES + nb];
            u16 hi, lo; split_bf(v, hi, lo);
            bhi[j] = (short)hi;
            blo[j] = (short)lo;
        }
        acc = __builtin_amdgcn_mfma_f32_32x32x16_bf16(ahi, bhi, acc, 0, 0, 0);
        acc = __builtin_amdgcn_mfma_f32_32x32x16_bf16(ahi, blo, acc, 0, 0, 0);
        acc = __builtin_amdgcn_mfma_f32_32x32x16_bf16(alo, bhi, acc, 0, 0, 0);
    }

    float* Pk = P + (size_t)kz * (ATT_H * N_ANTES);
    #pragma unroll
    for (int q = 0; q < 16; ++q) {
        int row = mt * 32 + (q & 3) + 8 * (q >> 2) + 4 * (lane >> 5);
        Pk[(size_t)row * N_ANTES + nb] = acc[q];
    }
}

__global__ __launch_bounds__(256) void k_reduce4(const float* __restrict__ P,
                                                 float* __restrict__ preT)
{
    int gid = blockIdx.x * 256 + threadIdx.x;
    const int SZ = ATT_H * N_ANTES;
    preT[gid] = (P[gid] + P[gid + SZ]) + (P[gid + 2 * SZ] + P[gid + 3 * SZ]);
}

// ---------------------------------------------------------------------------
// Pack w_hh into B-fragment order (bf16 hi/lo), gate-interleaved columns.
// ---------------------------------------------------------------------------
__global__ __launch_bounds__(256) void k_packWf(const float* __restrict__ w_hh,
                                                u16* __restrict__ Wf_hi,
                                                u16* __restrict__ Wf_lo)
{
    int gid = blockIdx.x * 256 + threadIdx.x;      // 0..262143
    int j    = gid & 7;
    int l    = (gid >> 3) & 63;
    int kt   = (gid >> 9) & 15;
    int nsub = (gid >> 13) & 1;
    int cb   = gid >> 14;
    int k  = kt * 16 + kin_of(l, j);
    int cc = nsub * 32 + (l & 31);
    int jj = cb * 16 + (cc >> 2);
    int g  = cc & 3;
    int J  = g * 256 + jj;
    float v = w_hh[(size_t)J * 256 + k];
    u16 hi = f2bf(v);
    Wf_hi[gid] = hi;
    Wf_lo[gid] = f2bf(v - bf2f(hi));
}

// ---------------------------------------------------------------------------
// Pack fp32 h into A-fragment order (bf16 hi/lo).
// ---------------------------------------------------------------------------
__global__ __launch_bounds__(256) void k_packHf(const float* __restrict__ h,
                                                u16* __restrict__ Hf_hi,
                                                u16* __restrict__ Hf_lo)
{
    int gid = blockIdx.x * 256 + threadIdx.x;      // 0..1048575
    int j  = gid & 7;
    int l  = (gid >> 3) & 63;
    int kt = (gid >> 9) & 15;
    int mt = gid >> 13;
    int m = mt * 32 + (l & 31);
    int k = kt * 16 + kin_of(l, j);
    float v = h[(size_t)m * 256 + k];
    u16 hi = f2bf(v);
    Hf_hi[gid] = hi;
    Hf_lo[gid] = f2bf(v - bf2f(hi));
}

// ---------------------------------------------------------------------------
// Fused LSTM step via MFMA (bf16x3): grid (32 rb, 16 cb), 256 threads.
// ---------------------------------------------------------------------------
__global__ __launch_bounds__(256) void k_zgemm(
    const u16* __restrict__ Hf_hi_r, const u16* __restrict__ Hf_lo_r,
    u16* __restrict__ Hf_hi_w, u16* __restrict__ Hf_lo_w,
    const u16* __restrict__ Wf_hi, const u16* __restrict__ Wf_lo,
    float* __restrict__ c,
    const float* __restrict__ rowsum, const float* __restrict__ b_ih,
    const float* __restrict__ b_hh, const float* __restrict__ S,
    const int* __restrict__ idx_buf, int t, float* __restrict__ e_acc_t)
{
    __shared__ __align__(16) float z_lds[128][68];
    __shared__ float red[256];
    const int tid  = threadIdx.x;
    const int lane = tid & 63;
    const int msub = tid >> 6;
    const int rb = blockIdx.x;       // 0..31  (128 rows each)
    const int cb = blockIdx.y;       // 0..15  (64 packed cols each)
    const int mt = rb * 4 + msub;

    floatx16 acc0 = {0,0,0,0,0,0,0,0,0,0,0,0,0,0,0,0};
    floatx16 acc1 = {0,0,0,0,0,0,0,0,0,0,0,0,0,0,0,0};
    const size_t aoff  = (size_t)mt * 16 * 512 + lane * 8;
    const size_t boff0 = (size_t)(cb * 2 + 0) * 16 * 512 + lane * 8;
    const size_t boff1 = (size_t)(cb * 2 + 1) * 16 * 512 + lane * 8;

    #pragma unroll 4
    for (int kt = 0; kt < 16; ++kt) {
        short8 ahi = *(const short8*)(Hf_hi_r + aoff  + kt * 512);
        short8 alo = *(const short8*)(Hf_lo_r + aoff  + kt * 512);
        short8 b0h = *(const short8*)(Wf_hi   + boff0 + kt * 512);
        short8 b0l = *(const short8*)(Wf_lo   + boff0 + kt * 512);
        short8 b1h = *(const short8*)(Wf_hi   + boff1 + kt * 512);
        short8 b1l = *(const short8*)(Wf_lo   + boff1 + kt * 512);
        acc0 = __builtin_amdgcn_mfma_f32_32x32x16_bf16(ahi, b0h, acc0, 0, 0, 0);
        acc0 = __builtin_amdgcn_mfma_f32_32x32x16_bf16(ahi, b0l, acc0, 0, 0, 0);
        acc0 = __builtin_amdgcn_mfma_f32_32x32x16_bf16(alo, b0h, acc0, 0, 0, 0);
        acc1 = __builtin_amdgcn_mfma_f32_32x32x16_bf16(ahi, b1h, acc1, 0, 0, 0);
        acc1 = __builtin_amdgcn_mfma_f32_32x32x16_bf16(ahi, b1l, acc1, 0, 0, 0);
        acc1 = __builtin_amdgcn_mfma_f32_32x32x16_bf16(alo, b1h, acc1, 0, 0, 0);
    }

    // C/D layout (HW-verified): col = lane&31, row = (q&3)+8*(q>>2)+4*(lane>>5)
    #pragma unroll
    for (int q = 0; q < 16; ++q) {
        int row = msub * 32 + (q & 3) + 8 * (q >> 2) + 4 * (lane >> 5);
        z_lds[row][lane & 31]        = acc0[q];
        z_lds[row][32 + (lane & 31)] = acc1[q];
    }
    __syncthreads();

    // ---- fused gates: thread = (jj_l, rg) handles 8 rows of one enc-col ----
    const int jj_l = tid & 15, rg = tid >> 4;
    const int Jc = cb * 16 + jj_l;           // enc-dim column (0..255)
    float rs[4], bs[4];
    #pragma unroll
    for (int g = 0; g < 4; ++g) {
        int J = g * 256 + Jc;
        rs[g] = rowsum[J];
        bs[g] = b_ih[J] + b_hh[J];
    }
    const int idxp = (t > 0) ? idx_buf[t - 1] : 0;
    float esum = 0.f;
    #pragma unroll
    for (int p = 0; p < 8; ++p) {
        int r = rg * 8 + p;
        int rglob = rb * 128 + r;
        float a = (t > 0) ? S[(size_t)rglob * N_ANTES + idxp] : 1.f;
        float4 z4 = *(const float4*)&z_lds[r][jj_l * 4];
        float zi = z4.x + fmaf(a, rs[0], bs[0]);
        float zf = z4.y + fmaf(a, rs[1], bs[1]);
        float zg = z4.z + fmaf(a, rs[2], bs[2]);
        float zo = z4.w + fmaf(a, rs[3], bs[3]);
        size_t coff = (size_t)rglob * 256 + Jc;
        float cn = fsig(zf) * c[coff] + fsig(zi) * ftanh(zg);
        float hn = fsig(zo) * ftanh(cn);
        c[coff] = cn;
        esum += hn;
        // write h back in A-fragment order (inverse of kin_of; bijective)
        u16 hi = f2bf(hn);
        u16 lo = f2bf(hn - bf2f(hi));
        int mtw    = rglob >> 5;
        int lane_a = (rglob & 31) + 32 * ((Jc >> 2) & 1);
        int ktw    = Jc >> 4;
        int jw     = (Jc & 3) + ((Jc >> 3) & 1) * 4;
        size_t off = (((size_t)mtw * 16 + ktw) * 64 + lane_a) * 8 + jw;
        Hf_hi_w[off] = hi;
        Hf_lo_w[off] = lo;
    }
    red[tid] = esum;
    __syncthreads();
    if (tid < 16) {
        float s = 0.f;
        #pragma unroll
        for (int q = 0; q < 16; ++q) s += red[tid + q * 16];
        atomicAdd(&e_acc_t[Jc - jj_l + tid], s);   // = e_acc_t[cb*16 + tid]
    }
}

// ---------------------------------------------------------------------------
// Fused attention: scores + log-softmax + argmax in ONE kernel (last-block).
// ---------------------------------------------------------------------------
__global__ __launch_bounds__(256) void k_att(
    const float* __restrict__ preT, const float* __restrict__ e_accum_t,
    const float* __restrict__ WbT, const float* __restrict__ att_b1,
    const float* __restrict__ att_w2, const float* __restrict__ att_b2,
    float* __restrict__ scores, float* __restrict__ out_t,
    int* __restrict__ idx_t, int* __restrict__ cnt)
{
    __shared__ float e_lds[256];
    __shared__ float u[256];
    __shared__ float w2s[256];
    __shared__ float red[256];
    const int tid = threadIdx.x;
    e_lds[tid] = e_accum_t[tid] * (1.f / (float)N_TRAIN);
    w2s[tid] = att_w2[tid];
    __syncthreads();

    float uacc = att_b1[tid];
    for (int k = 0; k < 256; ++k)
        uacc = fmaf(e_lds[k], WbT[(size_t)k * 256 + tid], uacc);
    u[tid] = uacc;
    __syncthreads();

    const int pl = tid & 31, jq = tid >> 5;   // 8-way j split
    const int p = blockIdx.x * 32 + pl;
    float sc = 0.f;
    #pragma unroll 4
    for (int j = jq; j < 256; j += 8) {
        float v = preT[(size_t)j * N_ANTES + p] + u[j];
        sc = fmaf(fmaxf(v, 0.f), w2s[j], sc);
    }
    red[tid] = sc;
    __syncthreads();
    if (tid < 32) {
        float s = att_b2[0];
        #pragma unroll
        for (int q = 0; q < 8; ++q) s += red[tid + q * 32];
        scores[blockIdx.x * 32 + tid] = s;
    }

    // ---- last-block handshake ----
    __threadfence();
    __syncthreads();
    __shared__ int is_last;
    if (tid == 0)
        is_last = (atomicAdd(cnt, 1) == (int)gridDim.x - 1);
    __syncthreads();
    if (!is_last) return;
    __threadfence();

    // ---- phase 2: log-softmax + argmax over 2048 scores (one block) ----
    __shared__ float smax[256];
    __shared__ int   sidx[256];
    __shared__ float ssum[256];

    float sv[8];
    #pragma unroll
    for (int i = 0; i < 8; ++i) sv[i] = scores[tid * 8 + i];

    float lmax = -INFINITY; int lidx = 0;
    #pragma unroll
    for (int i = 0; i < 8; ++i)
        if (sv[i] > lmax) { lmax = sv[i]; lidx = tid * 8 + i; }
    smax[tid] = lmax; sidx[tid] = lidx;
    __syncthreads();
    for (int off = 128; off > 0; off >>= 1) {
        if (tid < off) {
            float ov = smax[tid + off]; int oi = sidx[tid + off];
            if (ov > smax[tid] || (ov == smax[tid] && oi < sidx[tid])) {
                smax[tid] = ov; sidx[tid] = oi;
            }
        }
        __syncthreads();
    }
    const float gmax = smax[0];
    const int gidx = sidx[0];

    float lsum = 0.f;
    #pragma unroll
    for (int i = 0; i < 8; ++i) lsum += __expf(sv[i] - gmax);
    ssum[tid] = lsum;
    __syncthreads();
    for (int off = 128; off > 0; off >>= 1) {
        if (tid < off) ssum[tid] += ssum[tid + off];
        __syncthreads();
    }
    const float lse = gmax + logf(ssum[0]);

    #pragma unroll
    for (int i = 0; i < 8; ++i)
        out_t[tid * 8 + i] = sv[i] - lse;
    if (tid == 0) {
        idx_t[0] = gidx;
        *cnt = 0;
    }
}

// ---------------------------------------------------------------------------
extern "C" void kernel_launch(void* const* d_in, const int* in_sizes, int n_in,
                              void* d_out, int out_size, void* d_ws, size_t ws_size,
                              hipStream_t stream)
{
    (void)in_sizes; (void)n_in; (void)out_size; (void)ws_size;
    const float* context = (const float*)d_in[0];
    const float* S       = (const float*)d_in[1];
    const float* enc_w1  = (const float*)d_in[2];
    const float* enc_b1  = (const float*)d_in[3];
    const float* enc_w2  = (const float*)d_in[4];
    const float* enc_b2  = (const float*)d_in[5];
    const float* w_ih    = (const float*)d_in[6];
    const float* w_hh    = (const float*)d_in[7];
    const float* b_ih    = (const float*)d_in[8];
    const float* b_hh    = (const float*)d_in[9];
    const float* att_w1  = (const float*)d_in[10];
    const float* att_b1  = (const float*)d_in[11];
    const float* att_w2  = (const float*)d_in[12];
    const float* att_b2  = (const float*)d_in[13];
    float* out = (float*)d_out;
    float* ws  = (float*)d_ws;

    // ws layout (float offsets), footprint unchanged:
    float* P      = ws;                         // 4 x 512K fp32 partials
    float* h_fp32 = ws;                         // (after P dead)
    float* c      = ws + 1048576;
    float* hid1   = ws + 2097152;
    float* preT   = ws + 3145728;
    u16* Af_hi  = (u16*)(ws + 2097152);         // dead before encoder gemm1
    u16* Af_lo  = (u16*)(ws + 2621440);
    u16* Hf_hi1 = (u16*)(ws + 0);
    u16* Hf_lo1 = (u16*)(ws + 524288);
    u16* Hf_hi0 = (u16*)(ws + 2097152);
    u16* Hf_lo0 = (u16*)(ws + 2621440);
    u16* Wf_hi  = (u16*)(ws + 3670016);
    u16* Wf_lo  = (u16*)(ws + 3801088);
    int*   cnt    = (int*)(ws + 4718592);
    float* rowsum = ws + 4984832;               // 1,024
    float* e_acc  = ws + 4985856;               // 4,096
    float* scores = ws + 4989952;               // 2,048
    float* WbT    = ws + 4992000;               // 65,536
    int*   idxbuf = (int*)(ws + 5057536);       // 16

    k_rowsum<<<1024, 256, 0, stream>>>(w_ih, rowsum);
    k_wbT<<<256, 256, 0, stream>>>(att_w1, WbT);
    k_packWf<<<1024, 256, 0, stream>>>(w_hh, Wf_hi, Wf_lo);

    // ---- preT = Wa @ S via MFMA bf16x3 split-K (512 blocks, 2048 waves) ----
    k_packAf<<<4096, 256, 0, stream>>>(att_w1, Af_hi, Af_lo);
    dim3 gp(PSPLIT, N_ANTES / 64, 4);
    k_gemm_preT<<<gp, 256, 0, stream>>>(Af_hi, Af_lo, S, P);
    k_reduce4<<<(ATT_H * N_ANTES) / 256, 256, 0, stream>>>(P, preT);

    // P region dead now: clear state
    hipMemsetAsync(c, 0, (size_t)N_TRAIN * ENC * sizeof(float), stream);
    hipMemsetAsync(e_acc, 0, (size_t)MAX_LEN * ENC * sizeof(float), stream);
    hipMemsetAsync(cnt, 0, sizeof(int), stream);

    // ---- encoder (Af dead -> hid1 region reusable) ----
    dim3 g1(N_TRAIN / 64, N_HID / 64);
    gemm_abT<true><<<g1, 256, 0, stream>>>(context, enc_w1, enc_b1, hid1,
                                           N_TRAIN, N_HID, N_FEAT, N_FEAT, N_FEAT, N_HID);
    dim3 g2(N_TRAIN / 64, ENC / 64);
    gemm_abT<false><<<g2, 256, 0, stream>>>(hid1, enc_w2, enc_b2, h_fp32,
                                            N_TRAIN, ENC, N_HID, N_HID, N_HID, ENC);
    // pack h0 fragments (overwrites hid1, dead after gemm2)
    k_packHf<<<4096, 256, 0, stream>>>(h_fp32, Hf_hi0, Hf_lo0);

    dim3 gz(32, 16);
    for (int t = 0; t < MAX_LEN; ++t) {
        const u16 *hr, *lr; u16 *hw, *lw;
        if ((t & 1) == 0) { hr = Hf_hi0; lr = Hf_lo0; hw = Hf_hi1; lw = Hf_lo1; }
        else              { hr = Hf_hi1; lr = Hf_lo1; hw = Hf_hi0; lw = Hf_lo0; }
        k_zgemm<<<gz, 256, 0, stream>>>(hr, lr, hw, lw, Wf_hi, Wf_lo, c,
                                        rowsum, b_ih, b_hh, S, idxbuf, t,
                                        e_acc + t * 256);
        k_att<<<N_ANTES / 32, 256, 0, stream>>>(preT, e_acc + t * 256, WbT,
                                                att_b1, att_w2, att_b2, scores,
                                                out + t * N_ANTES, idxbuf + t, cnt);
    }
}

// Round 9
// 694.427 us; speedup vs baseline: 2.2843x; 1.0145x over previous
//
#include <hip/hip_runtime.h>
#include <hip/hip_bf16.h>
#include <math.h>

// Shapes
#define N_TRAIN 4096
#define N_FEAT  64
#define N_HID   256
#define ENC     256
#define N_ANTES 2048
#define ATT_H   256
#define MAX_LEN 16

typedef unsigned int u32;
typedef unsigned short u16;
typedef short short8 __attribute__((ext_vector_type(8)));
typedef float floatx16 __attribute__((ext_vector_type(16)));

__device__ __forceinline__ float fsig(float x)  { return 1.f / (1.f + __expf(-x)); }
__device__ __forceinline__ float ftanh(float x) { return 2.f / (1.f + __expf(-2.f * x)) - 1.f; }

// bf16 round-to-nearest-even helpers
__device__ __forceinline__ u16 f2bf(float x) {
    u32 b = __float_as_uint(x);
    return (u16)((b + 0x7FFFu + ((b >> 16) & 1u)) >> 16);
}
__device__ __forceinline__ float bf2f(u16 h) {
    return __uint_as_float(((u32)h) << 16);
}
// cheap truncation hi/lo split (residual v-hi exact in fp32)
__device__ __forceinline__ void split_bf(float v, u16& hi, u16& lo) {
    u32 b = __float_as_uint(v);
    hi = (u16)(b >> 16);
    float r = v - __uint_as_float(b & 0xFFFF0000u);
    lo = (u16)(__float_as_uint(r) >> 16);
}

// A/B fragment k-offset for v_mfma_f32_32x32x16_bf16 (2xK stacked CDNA layout):
// lane l, elem j (0..7) -> k = 4*(l>>5) + (j&3) + 8*(j>>2)
__device__ __forceinline__ int kin_of(int l, int j) {
    return ((l >> 5) << 2) + (j & 3) + ((j >> 2) << 3);
}

// ---------------------------------------------------------------------------
// Tiled GEMM: C[m,n] = act(bias[n] + sum_k A[m,k] * B[n,k]); 64x64x16 tiles.
// (encoder only)
// ---------------------------------------------------------------------------
template <bool RELU>
__global__ __launch_bounds__(256) void gemm_abT(
    const float* __restrict__ A, const float* __restrict__ B,
    const float* __restrict__ bias, float* __restrict__ C,
    int M, int N, int K, int lda, int ldb, int ldc)
{
    __shared__ __align__(16) float As[16][68];
    __shared__ __align__(16) float Bs[16][68];
    const int tid = threadIdx.x;
    const int m0 = blockIdx.x * 64, n0 = blockIdx.y * 64;
    const int tx = tid & 15, ty = tid >> 4;
    const int kl = tid & 15, rl = tid >> 4;
    float acc[4][4] = {};

    for (int k0 = 0; k0 < K; k0 += 16) {
        #pragma unroll
        for (int pp = 0; pp < 4; ++pp) {
            int r = rl + pp * 16;
            As[kl][r] = A[(size_t)(m0 + r) * lda + k0 + kl];
            Bs[kl][r] = B[(size_t)(n0 + r) * ldb + k0 + kl];
        }
        __syncthreads();
        #pragma unroll
        for (int k = 0; k < 16; ++k) {
            float4 av = *(const float4*)&As[k][ty * 4];
            float4 bv = *(const float4*)&Bs[k][tx * 4];
            float a4[4] = {av.x, av.y, av.z, av.w};
            float b4[4] = {bv.x, bv.y, bv.z, bv.w};
            #pragma unroll
            for (int i = 0; i < 4; ++i)
                #pragma unroll
                for (int j = 0; j < 4; ++j)
                    acc[i][j] = fmaf(a4[i], b4[j], acc[i][j]);
        }
        __syncthreads();
    }
    #pragma unroll
    for (int i = 0; i < 4; ++i) {
        int m = m0 + ty * 4 + i;
        #pragma unroll
        for (int j = 0; j < 4; ++j) {
            int n = n0 + tx * 4 + j;
            float v = acc[i][j] + bias[n];
            if (RELU) v = fmaxf(v, 0.f);
            C[(size_t)m * ldc + n] = v;
        }
    }
}

// ---------------------------------------------------------------------------
// rowsum[j] = sum_k w_ih[j, k]
// ---------------------------------------------------------------------------
__global__ __launch_bounds__(256) void k_rowsum(const float* __restrict__ w_ih,
                                                float* __restrict__ rowsum)
{
    __shared__ float red[256];
    const int j = blockIdx.x, tid = threadIdx.x;
    float s = 0.f;
    for (int i = tid; i < N_ANTES; i += 256) s += w_ih[(size_t)j * N_ANTES + i];
    red[tid] = s; __syncthreads();
    for (int off = 128; off > 0; off >>= 1) {
        if (tid < off) red[tid] += red[tid + off];
        __syncthreads();
    }
    if (tid == 0) rowsum[j] = red[0];
}

// ---------------------------------------------------------------------------
// WbT[k*256 + j] = att_w1[j*(N_TRAIN+ENC) + N_TRAIN + k]
// ---------------------------------------------------------------------------
__global__ __launch_bounds__(256) void k_wbT(const float* __restrict__ att_w1,
                                             float* __restrict__ WbT)
{
    int gid = blockIdx.x * 256 + threadIdx.x;  // 0..65535
    int j = gid >> 8, k = gid & 255;
    WbT[(size_t)k * 256 + j] = att_w1[(size_t)j * (N_TRAIN + ENC) + N_TRAIN + k];
}

// ---------------------------------------------------------------------------
// Pack Wa = att_w1[:, :N_TRAIN] (256x4096) into A-fragment order (bf16 hi/lo).
// Af[((mt*256 + kt)*64 + l)*8 + j] = Wa[mt*32 + (l&31)][kt*16 + kin(l,j)]
// ---------------------------------------------------------------------------
__global__ __launch_bounds__(256) void k_packAf(const float* __restrict__ att_w1,
                                                u16* __restrict__ Af_hi,
                                                u16* __restrict__ Af_lo)
{
    int gid = blockIdx.x * 256 + threadIdx.x;   // 0..1048575
    int j  = gid & 7;
    int l  = (gid >> 3) & 63;
    int kt = (gid >> 9) & 255;
    int mt = gid >> 17;
    int m = mt * 32 + (l & 31);
    int k = kt * 16 + kin_of(l, j);
    float v = att_w1[(size_t)m * (N_TRAIN + ENC) + k];
    u16 hi, lo; split_bf(v, hi, lo);
    Af_hi[gid] = hi;
    Af_lo[gid] = lo;
}

// ---------------------------------------------------------------------------
// preT = Wa @ S via MFMA bf16x3, split-K=8. Grid (8 kz, 32 np, 4 mq), 256 thr.
// ONE 32x32 output job per wave: wave w -> mt = mq*2+(w&1), ni = w>>1.
// 2048 blocks' worth of waves = 16 waves/CU. Paired K-chunks (kz, kz+4)
// accumulate into buffer kz&3 via atomicAdd on pre-zeroed P: exactly 2
// commutative fp32 adds per location -> bitwise deterministic.
// ---------------------------------------------------------------------------
#define PSPLIT 8
__global__ __launch_bounds__(256) void k_gemm_preT(
    const u16* __restrict__ Af_hi, const u16* __restrict__ Af_lo,
    const float* __restrict__ S, float* __restrict__ P)
{
    const int tid = threadIdx.x, lane = tid & 63, w = tid >> 6;
    const int kz = blockIdx.x;          // 0..7
    const int np = blockIdx.y;          // 0..31
    const int mq = blockIdx.z;          // 0..3
    const int mt = mq * 2 + (w & 1);    // 0..7
    const int ni = w >> 1;              // 0..1
    const int nb = np * 64 + ni * 32 + (lane & 31);
    const int kb = 4 * (lane >> 5);
    floatx16 acc = {0,0,0,0,0,0,0,0,0,0,0,0,0,0,0,0};

    const int kt_beg = kz * 32, kt_end = kt_beg + 32;
    #pragma unroll 4
    for (int kt = kt_beg; kt < kt_end; ++kt) {
        size_t ao = (((size_t)mt * 256 + kt) * 64 + lane) * 8;
        short8 ahi = *(const short8*)(Af_hi + ao);
        short8 alo = *(const short8*)(Af_lo + ao);
        short8 bhi, blo;
        #pragma unroll
        for (int j = 0; j < 8; ++j) {
            int k = kt * 16 + kb + (j & 3) + 8 * (j >> 2);
            float v = S[(size_t)k * N_ANTES + nb];
            u16 hi, lo; split_bf(v, hi, lo);
            bhi[j] = (short)hi;
            blo[j] = (short)lo;
        }
        acc = __builtin_amdgcn_mfma_f32_32x32x16_bf16(ahi, bhi, acc, 0, 0, 0);
        acc = __builtin_amdgcn_mfma_f32_32x32x16_bf16(ahi, blo, acc, 0, 0, 0);
        acc = __builtin_amdgcn_mfma_f32_32x32x16_bf16(alo, bhi, acc, 0, 0, 0);
    }

    float* Pk = P + (size_t)(kz & 3) * (ATT_H * N_ANTES);
    #pragma unroll
    for (int q = 0; q < 16; ++q) {
        int row = mt * 32 + (q & 3) + 8 * (q >> 2) + 4 * (lane >> 5);
        atomicAdd(&Pk[(size_t)row * N_ANTES + nb], acc[q]);
    }
}

__global__ __launch_bounds__(256) void k_reduce4(const float* __restrict__ P,
                                                 float* __restrict__ preT)
{
    int gid = blockIdx.x * 256 + threadIdx.x;
    const int SZ = ATT_H * N_ANTES;
    preT[gid] = (P[gid] + P[gid + SZ]) + (P[gid + 2 * SZ] + P[gid + 3 * SZ]);
}

// ---------------------------------------------------------------------------
// Pack w_hh into B-fragment order (bf16 hi/lo), gate-interleaved columns.
// ---------------------------------------------------------------------------
__global__ __launch_bounds__(256) void k_packWf(const float* __restrict__ w_hh,
                                                u16* __restrict__ Wf_hi,
                                                u16* __restrict__ Wf_lo)
{
    int gid = blockIdx.x * 256 + threadIdx.x;      // 0..262143
    int j    = gid & 7;
    int l    = (gid >> 3) & 63;
    int kt   = (gid >> 9) & 15;
    int nsub = (gid >> 13) & 1;
    int cb   = gid >> 14;
    int k  = kt * 16 + kin_of(l, j);
    int cc = nsub * 32 + (l & 31);
    int jj = cb * 16 + (cc >> 2);
    int g  = cc & 3;
    int J  = g * 256 + jj;
    float v = w_hh[(size_t)J * 256 + k];
    u16 hi = f2bf(v);
    Wf_hi[gid] = hi;
    Wf_lo[gid] = f2bf(v - bf2f(hi));
}

// ---------------------------------------------------------------------------
// Pack fp32 h into A-fragment order (bf16 hi/lo).
// ---------------------------------------------------------------------------
__global__ __launch_bounds__(256) void k_packHf(const float* __restrict__ h,
                                                u16* __restrict__ Hf_hi,
                                                u16* __restrict__ Hf_lo)
{
    int gid = blockIdx.x * 256 + threadIdx.x;      // 0..1048575
    int j  = gid & 7;
    int l  = (gid >> 3) & 63;
    int kt = (gid >> 9) & 15;
    int mt = gid >> 13;
    int m = mt * 32 + (l & 31);
    int k = kt * 16 + kin_of(l, j);
    float v = h[(size_t)m * 256 + k];
    u16 hi = f2bf(v);
    Hf_hi[gid] = hi;
    Hf_lo[gid] = f2bf(v - bf2f(hi));
}

// ---------------------------------------------------------------------------
// Fused LSTM step via MFMA (bf16x3): 64x64 tile, grid (64 rb, 16 cb), 256 thr.
// 1024 blocks = 4 blocks/CU = 16 waves/CU (R8's 512-block version was 2/CU).
// Wave w: one 32x32 job, mt = rb*2+(w&1), ni = w>>1. Epilogue: 4 rows/thread.
// ---------------------------------------------------------------------------
__global__ __launch_bounds__(256) void k_zgemm(
    const u16* __restrict__ Hf_hi_r, const u16* __restrict__ Hf_lo_r,
    u16* __restrict__ Hf_hi_w, u16* __restrict__ Hf_lo_w,
    const u16* __restrict__ Wf_hi, const u16* __restrict__ Wf_lo,
    float* __restrict__ c,
    const float* __restrict__ rowsum, const float* __restrict__ b_ih,
    const float* __restrict__ b_hh, const float* __restrict__ S,
    const int* __restrict__ idx_buf, int t, float* __restrict__ e_acc_t)
{
    __shared__ __align__(16) float z_lds[64][68];
    __shared__ float red[256];
    const int tid  = threadIdx.x;
    const int lane = tid & 63;
    const int w    = tid >> 6;       // 0..3
    const int rb = blockIdx.x;       // 0..63  (64 rows each)
    const int cb = blockIdx.y;       // 0..15  (64 packed cols each)
    const int mt = rb * 2 + (w & 1); // 0..127
    const int ni = w >> 1;           // 0..1

    floatx16 acc = {0,0,0,0,0,0,0,0,0,0,0,0,0,0,0,0};
    const size_t aoff = (size_t)mt * 16 * 512 + lane * 8;
    const size_t boff = (size_t)(cb * 2 + ni) * 16 * 512 + lane * 8;

    #pragma unroll 4
    for (int kt = 0; kt < 16; ++kt) {
        short8 ahi = *(const short8*)(Hf_hi_r + aoff + kt * 512);
        short8 alo = *(const short8*)(Hf_lo_r + aoff + kt * 512);
        short8 bhi = *(const short8*)(Wf_hi   + boff + kt * 512);
        short8 blo = *(const short8*)(Wf_lo   + boff + kt * 512);
        acc = __builtin_amdgcn_mfma_f32_32x32x16_bf16(ahi, bhi, acc, 0, 0, 0);
        acc = __builtin_amdgcn_mfma_f32_32x32x16_bf16(ahi, blo, acc, 0, 0, 0);
        acc = __builtin_amdgcn_mfma_f32_32x32x16_bf16(alo, bhi, acc, 0, 0, 0);
    }

    // C/D layout (HW-verified): col = lane&31, row = (q&3)+8*(q>>2)+4*(lane>>5)
    #pragma unroll
    for (int q = 0; q < 16; ++q) {
        int row = (w & 1) * 32 + (q & 3) + 8 * (q >> 2) + 4 * (lane >> 5);
        z_lds[row][ni * 32 + (lane & 31)] = acc[q];
    }
    __syncthreads();

    // ---- fused gates: thread = (jj_l, rg) handles 4 rows of one enc-col ----
    const int jj_l = tid & 15, rg = tid >> 4;
    const int Jc = cb * 16 + jj_l;           // enc-dim column (0..255)
    float rs[4], bs[4];
    #pragma unroll
    for (int g = 0; g < 4; ++g) {
        int J = g * 256 + Jc;
        rs[g] = rowsum[J];
        bs[g] = b_ih[J] + b_hh[J];
    }
    const int idxp = (t > 0) ? idx_buf[t - 1] : 0;
    float esum = 0.f;
    #pragma unroll
    for (int p = 0; p < 4; ++p) {
        int r = rg * 4 + p;
        int rglob = rb * 64 + r;
        float a = (t > 0) ? S[(size_t)rglob * N_ANTES + idxp] : 1.f;
        float4 z4 = *(const float4*)&z_lds[r][jj_l * 4];
        float zi = z4.x + fmaf(a, rs[0], bs[0]);
        float zf = z4.y + fmaf(a, rs[1], bs[1]);
        float zg = z4.z + fmaf(a, rs[2], bs[2]);
        float zo = z4.w + fmaf(a, rs[3], bs[3]);
        size_t coff = (size_t)rglob * 256 + Jc;
        float cn = fsig(zf) * c[coff] + fsig(zi) * ftanh(zg);
        float hn = fsig(zo) * ftanh(cn);
        c[coff] = cn;
        esum += hn;
        // write h back in A-fragment order (inverse of kin_of; bijective)
        u16 hi = f2bf(hn);
        u16 lo = f2bf(hn - bf2f(hi));
        int mtw    = rglob >> 5;
        int lane_a = (rglob & 31) + 32 * ((Jc >> 2) & 1);
        int ktw    = Jc >> 4;
        int jw     = (Jc & 3) + ((Jc >> 3) & 1) * 4;
        size_t off = (((size_t)mtw * 16 + ktw) * 64 + lane_a) * 8 + jw;
        Hf_hi_w[off] = hi;
        Hf_lo_w[off] = lo;
    }
    red[tid] = esum;
    __syncthreads();
    if (tid < 16) {
        float s = 0.f;
        #pragma unroll
        for (int q = 0; q < 16; ++q) s += red[tid + q * 16];
        atomicAdd(&e_acc_t[Jc - jj_l + tid], s);   // = e_acc_t[cb*16 + tid]
    }
}

// ---------------------------------------------------------------------------
// Fused attention: scores + log-softmax + argmax in ONE kernel (last-block).
// ---------------------------------------------------------------------------
__global__ __launch_bounds__(256) void k_att(
    const float* __restrict__ preT, const float* __restrict__ e_accum_t,
    const float* __restrict__ WbT, const float* __restrict__ att_b1,
    const float* __restrict__ att_w2, const float* __restrict__ att_b2,
    float* __restrict__ scores, float* __restrict__ out_t,
    int* __restrict__ idx_t, int* __restrict__ cnt)
{
    __shared__ float e_lds[256];
    __shared__ float u[256];
    __shared__ float w2s[256];
    __shared__ float red[256];
    const int tid = threadIdx.x;
    e_lds[tid] = e_accum_t[tid] * (1.f / (float)N_TRAIN);
    w2s[tid] = att_w2[tid];
    __syncthreads();

    float uacc = att_b1[tid];
    for (int k = 0; k < 256; ++k)
        uacc = fmaf(e_lds[k], WbT[(size_t)k * 256 + tid], uacc);
    u[tid] = uacc;
    __syncthreads();

    const int pl = tid & 31, jq = tid >> 5;   // 8-way j split
    const int p = blockIdx.x * 32 + pl;
    float sc = 0.f;
    #pragma unroll 4
    for (int j = jq; j < 256; j += 8) {
        float v = preT[(size_t)j * N_ANTES + p] + u[j];
        sc = fmaf(fmaxf(v, 0.f), w2s[j], sc);
    }
    red[tid] = sc;
    __syncthreads();
    if (tid < 32) {
        float s = att_b2[0];
        #pragma unroll
        for (int q = 0; q < 8; ++q) s += red[tid + q * 32];
        scores[blockIdx.x * 32 + tid] = s;
    }

    // ---- last-block handshake ----
    __threadfence();
    __syncthreads();
    __shared__ int is_last;
    if (tid == 0)
        is_last = (atomicAdd(cnt, 1) == (int)gridDim.x - 1);
    __syncthreads();
    if (!is_last) return;
    __threadfence();

    // ---- phase 2: log-softmax + argmax over 2048 scores (one block) ----
    __shared__ float smax[256];
    __shared__ int   sidx[256];
    __shared__ float ssum[256];

    float sv[8];
    #pragma unroll
    for (int i = 0; i < 8; ++i) sv[i] = scores[tid * 8 + i];

    float lmax = -INFINITY; int lidx = 0;
    #pragma unroll
    for (int i = 0; i < 8; ++i)
        if (sv[i] > lmax) { lmax = sv[i]; lidx = tid * 8 + i; }
    smax[tid] = lmax; sidx[tid] = lidx;
    __syncthreads();
    for (int off = 128; off > 0; off >>= 1) {
        if (tid < off) {
            float ov = smax[tid + off]; int oi = sidx[tid + off];
            if (ov > smax[tid] || (ov == smax[tid] && oi < sidx[tid])) {
                smax[tid] = ov; sidx[tid] = oi;
            }
        }
        __syncthreads();
    }
    const float gmax = smax[0];
    const int gidx = sidx[0];

    float lsum = 0.f;
    #pragma unroll
    for (int i = 0; i < 8; ++i) lsum += __expf(sv[i] - gmax);
    ssum[tid] = lsum;
    __syncthreads();
    for (int off = 128; off > 0; off >>= 1) {
        if (tid < off) ssum[tid] += ssum[tid + off];
        __syncthreads();
    }
    const float lse = gmax + logf(ssum[0]);

    #pragma unroll
    for (int i = 0; i < 8; ++i)
        out_t[tid * 8 + i] = sv[i] - lse;
    if (tid == 0) {
        idx_t[0] = gidx;
        *cnt = 0;
    }
}

// ---------------------------------------------------------------------------
extern "C" void kernel_launch(void* const* d_in, const int* in_sizes, int n_in,
                              void* d_out, int out_size, void* d_ws, size_t ws_size,
                              hipStream_t stream)
{
    (void)in_sizes; (void)n_in; (void)out_size; (void)ws_size;
    const float* context = (const float*)d_in[0];
    const float* S       = (const float*)d_in[1];
    const float* enc_w1  = (const float*)d_in[2];
    const float* enc_b1  = (const float*)d_in[3];
    const float* enc_w2  = (const float*)d_in[4];
    const float* enc_b2  = (const float*)d_in[5];
    const float* w_ih    = (const float*)d_in[6];
    const float* w_hh    = (const float*)d_in[7];
    const float* b_ih    = (const float*)d_in[8];
    const float* b_hh    = (const float*)d_in[9];
    const float* att_w1  = (const float*)d_in[10];
    const float* att_b1  = (const float*)d_in[11];
    const float* att_w2  = (const float*)d_in[12];
    const float* att_b2  = (const float*)d_in[13];
    float* out = (float*)d_out;
    float* ws  = (float*)d_ws;

    // ws layout (float offsets), footprint unchanged:
    float* P      = ws;                         // 4 x 512K fp32 partials
    float* h_fp32 = ws;                         // (after P dead)
    float* c      = ws + 1048576;
    float* hid1   = ws + 2097152;
    float* preT   = ws + 3145728;
    u16* Af_hi  = (u16*)(ws + 2097152);         // dead before encoder gemm1
    u16* Af_lo  = (u16*)(ws + 2621440);
    u16* Hf_hi1 = (u16*)(ws + 0);
    u16* Hf_lo1 = (u16*)(ws + 524288);
    u16* Hf_hi0 = (u16*)(ws + 2097152);
    u16* Hf_lo0 = (u16*)(ws + 2621440);
    u16* Wf_hi  = (u16*)(ws + 3670016);
    u16* Wf_lo  = (u16*)(ws + 3801088);
    int*   cnt    = (int*)(ws + 4718592);
    float* rowsum = ws + 4984832;               // 1,024
    float* e_acc  = ws + 4985856;               // 4,096
    float* scores = ws + 4989952;               // 2,048
    float* WbT    = ws + 4992000;               // 65,536
    int*   idxbuf = (int*)(ws + 5057536);       // 16

    k_rowsum<<<1024, 256, 0, stream>>>(w_ih, rowsum);
    k_wbT<<<256, 256, 0, stream>>>(att_w1, WbT);
    k_packWf<<<1024, 256, 0, stream>>>(w_hh, Wf_hi, Wf_lo);

    // ---- preT = Wa @ S via MFMA bf16x3 split-K=8 (1024 blocks) ----
    k_packAf<<<4096, 256, 0, stream>>>(att_w1, Af_hi, Af_lo);
    hipMemsetAsync(P, 0, (size_t)4 * ATT_H * N_ANTES * sizeof(float), stream);
    dim3 gp(PSPLIT, N_ANTES / 64, 4);
    k_gemm_preT<<<gp, 256, 0, stream>>>(Af_hi, Af_lo, S, P);
    k_reduce4<<<(ATT_H * N_ANTES) / 256, 256, 0, stream>>>(P, preT);

    // P region dead now: clear state
    hipMemsetAsync(c, 0, (size_t)N_TRAIN * ENC * sizeof(float), stream);
    hipMemsetAsync(e_acc, 0, (size_t)MAX_LEN * ENC * sizeof(float), stream);
    hipMemsetAsync(cnt, 0, sizeof(int), stream);

    // ---- encoder (Af dead -> hid1 region reusable) ----
    dim3 g1(N_TRAIN / 64, N_HID / 64);
    gemm_abT<true><<<g1, 256, 0, stream>>>(context, enc_w1, enc_b1, hid1,
                                           N_TRAIN, N_HID, N_FEAT, N_FEAT, N_FEAT, N_HID);
    dim3 g2(N_TRAIN / 64, ENC / 64);
    gemm_abT<false><<<g2, 256, 0, stream>>>(hid1, enc_w2, enc_b2, h_fp32,
                                            N_TRAIN, ENC, N_HID, N_HID, N_HID, ENC);
    // pack h0 fragments (overwrites hid1, dead after gemm2)
    k_packHf<<<4096, 256, 0, stream>>>(h_fp32, Hf_hi0, Hf_lo0);

    dim3 gz(64, 16);
    for (int t = 0; t < MAX_LEN; ++t) {
        const u16 *hr, *lr; u16 *hw, *lw;
        if ((t & 1) == 0) { hr = Hf_hi0; lr = Hf_lo0; hw = Hf_hi1; lw = Hf_lo1; }
        else              { hr = Hf_hi1; lr = Hf_lo1; hw = Hf_hi0; lw = Hf_lo0; }
        k_zgemm<<<gz, 256, 0, stream>>>(hr, lr, hw, lw, Wf_hi, Wf_lo, c,
                                        rowsum, b_ih, b_hh, S, idxbuf, t,
                                        e_acc + t * 256);
        k_att<<<N_ANTES / 32, 256, 0, stream>>>(preT, e_acc + t * 256, WbT,
                                                att_b1, att_w2, att_b2, scores,
                                                out + t * N_ANTES, idxbuf + t, cnt);
    }
}